// Round 2
// baseline (11590.587 us; speedup 1.0000x reference)
//
#include <hip/hip_runtime.h>

#define NN 100000
#define NE 1600000
#define NB ((NN + 255) / 256)   // 391 blocks over nodes

// ---------------- CSR build ----------------
__global__ __launch_bounds__(256) void k_hist(const int* __restrict__ ei, int* __restrict__ deg, int E) {
    int e = blockIdx.x * 256 + threadIdx.x;
    if (e < E) atomicAdd(&deg[ei[e]], 1);
}

__global__ __launch_bounds__(256) void k_scan1(const int* __restrict__ deg, int* __restrict__ offs,
                                               int* __restrict__ bsums, int n) {
    __shared__ int s[256];
    int tid = threadIdx.x;
    int i = blockIdx.x * 256 + tid;
    int v = (i < n) ? deg[i] : 0;
    int acc = v;
    s[tid] = acc;
    __syncthreads();
    #pragma unroll
    for (int off = 1; off < 256; off <<= 1) {
        int t = (tid >= off) ? s[tid - off] : 0;
        __syncthreads();
        acc += t;
        s[tid] = acc;
        __syncthreads();
    }
    if (i < n) offs[i] = acc - v;             // exclusive
    if (tid == 255) bsums[blockIdx.x] = acc;  // block total
}

__global__ __launch_bounds__(512) void k_scan2(int* __restrict__ bsums, int nb) {
    __shared__ int s[512];
    int tid = threadIdx.x;
    int v = (tid < nb) ? bsums[tid] : 0;
    int acc = v;
    s[tid] = acc;
    __syncthreads();
    #pragma unroll
    for (int off = 1; off < 512; off <<= 1) {
        int t = (tid >= off) ? s[tid - off] : 0;
        __syncthreads();
        acc += t;
        s[tid] = acc;
        __syncthreads();
    }
    bsums[tid] = acc - v;  // exclusive
}

__global__ __launch_bounds__(256) void k_scan3(int* __restrict__ offs, const int* __restrict__ bsums, int n) {
    int i = blockIdx.x * 256 + threadIdx.x;
    if (i < n) offs[i] += bsums[blockIdx.x];
}

__global__ __launch_bounds__(256) void k_scatter(const int* __restrict__ ei, const int* __restrict__ offs,
                                                 int* __restrict__ cursor, int* __restrict__ sorted, int E) {
    int e = blockIdx.x * 256 + threadIdx.x;
    if (e >= E) return;
    int r = ei[e];
    int p = offs[r] + atomicAdd(&cursor[r], 1);
    sorted[p] = e;
}

// ---------------- precompute Wc = W1b @ W2a[32:96], bc = b1b @ W2a[32:96] ----------------
__global__ __launch_bounds__(256) void k_prep(const float* __restrict__ W1b, const float* __restrict__ b1b,
                                              const float* __restrict__ W2a,
                                              float* __restrict__ Wc, float* __restrict__ bc) {
    int t = blockIdx.x * 256 + threadIdx.x;  // 0..4095
    int r = t >> 6, c = t & 63;
    float a = 0.f;
    for (int k = 0; k < 64; ++k) a += W1b[r * 64 + k] * W2a[(32 + k) * 64 + c];
    Wc[t] = a;
    if (t < 64) {
        float bacc = 0.f;
        for (int k = 0; k < 64; ++k) bacc += b1b[k] * W2a[(32 + k) * 64 + t];
        bc[t] = bacc;
    }
}

// ---------------- precompute xa = x @ W1a[0:32] + b1a ----------------
__global__ __launch_bounds__(256) void k_xa(const float* __restrict__ x, const float* __restrict__ W1a,
                                            const float* __restrict__ b1a, float* __restrict__ xa, int N) {
    __shared__ float sW[32 * 64];
    __shared__ float sb[64];
    for (int i = threadIdx.x; i < 32 * 64; i += 256) sW[i] = W1a[i];
    if (threadIdx.x < 64) sb[threadIdx.x] = b1a[threadIdx.x];
    __syncthreads();
    int i = blockIdx.x * 256 + threadIdx.x;
    if (i >= N) return;
    float h[64];
    #pragma unroll
    for (int j = 0; j < 64; ++j) h[j] = sb[j];
    const float* xrow = x + (size_t)i * 32;
    #pragma unroll
    for (int k4 = 0; k4 < 8; ++k4) {
        float4 v = *(const float4*)(xrow + k4 * 4);
        float vv[4] = {v.x, v.y, v.z, v.w};
        #pragma unroll
        for (int c = 0; c < 4; ++c) {
            const float4* wr = (const float4*)&sW[(k4 * 4 + c) * 64];
            float val = vv[c];
            #pragma unroll
            for (int j4 = 0; j4 < 16; ++j4) {
                float4 w = wr[j4];
                h[j4 * 4 + 0] += val * w.x; h[j4 * 4 + 1] += val * w.y;
                h[j4 * 4 + 2] += val * w.z; h[j4 * 4 + 3] += val * w.w;
            }
        }
    }
    float4* xap = (float4*)(xa + (size_t)i * 64);
    #pragma unroll
    for (int q = 0; q < 16; ++q)
        xap[q] = make_float4(h[q * 4], h[q * 4 + 1], h[q * 4 + 2], h[q * 4 + 3]);
}

// ---------------- fused per-node: edge gather+MLP+sum, then node MLP ----------------
template <int USE_XA>
__global__ __launch_bounds__(256) void k_fused(
    const float* __restrict__ x, const int* __restrict__ ei, const float* __restrict__ ea,
    const float* __restrict__ xa,
    const float* __restrict__ W1a, const float* __restrict__ b1a,
    const float* __restrict__ Wc, const float* __restrict__ bc,
    const float* __restrict__ W2a, const float* __restrict__ b2a,
    const float* __restrict__ W2b, const float* __restrict__ b2b,
    const int* __restrict__ deg, const int* __restrict__ offs, const int* __restrict__ sorted,
    float* __restrict__ out, int N)
{
    __shared__ float sW1aB[32 * 64];                 // W1a rows 32..63 (edge_attr part)
    __shared__ float sW1aA[USE_XA ? 4 : 32 * 64];    // W1a rows 0..31 (only if no xa)
    __shared__ float sWc[64 * 64];
    __shared__ float sW2ax[32 * 64];                 // W2a rows 0..31 (x part)
    __shared__ float sW2b[64 * 32];
    __shared__ float sb1a[64];
    __shared__ float sbcb2a[64];
    __shared__ float sb2a[64];
    __shared__ float sb2b[32];
    for (int i = threadIdx.x; i < 32 * 64; i += 256) {
        sW1aB[i] = W1a[32 * 64 + i];
        if (!USE_XA) sW1aA[i] = W1a[i];
        sW2ax[i] = W2a[i];
    }
    for (int i = threadIdx.x; i < 64 * 64; i += 256) sWc[i] = Wc[i];
    for (int i = threadIdx.x; i < 64 * 32; i += 256) sW2b[i] = W2b[i];
    if (threadIdx.x < 64) {
        sb1a[threadIdx.x] = b1a[threadIdx.x];
        sbcb2a[threadIdx.x] = bc[threadIdx.x] + b2a[threadIdx.x];
        sb2a[threadIdx.x] = b2a[threadIdx.x];
    }
    if (threadIdx.x < 32) sb2b[threadIdx.x] = b2b[threadIdx.x];
    __syncthreads();

    int i = blockIdx.x * 256 + threadIdx.x;
    if (i >= N) return;
    int d = deg[i], start = offs[i];

    float S[64];
    #pragma unroll
    for (int j = 0; j < 64; ++j) S[j] = 0.f;

    #pragma unroll 1
    for (int kk = 0; kk < d; ++kk) {
        int e = sorted[start + kk];
        int col = ei[NE + e];
        float h[64];
        if (USE_XA) {
            const float4* xap = (const float4*)(xa + (size_t)col * 64);
            #pragma unroll
            for (int q = 0; q < 16; ++q) {
                float4 v = xap[q];
                h[q * 4 + 0] = v.x; h[q * 4 + 1] = v.y; h[q * 4 + 2] = v.z; h[q * 4 + 3] = v.w;
            }
        } else {
            #pragma unroll
            for (int j = 0; j < 64; ++j) h[j] = sb1a[j];
            const float* xrow = x + (size_t)col * 32;
            #pragma unroll
            for (int k4 = 0; k4 < 8; ++k4) {
                float4 v = *(const float4*)(xrow + k4 * 4);
                float vv[4] = {v.x, v.y, v.z, v.w};
                #pragma unroll
                for (int c = 0; c < 4; ++c) {
                    const float4* wr = (const float4*)&sW1aA[(k4 * 4 + c) * 64];
                    float val = vv[c];
                    #pragma unroll
                    for (int j4 = 0; j4 < 16; ++j4) {
                        float4 w = wr[j4];
                        h[j4 * 4 + 0] += val * w.x; h[j4 * 4 + 1] += val * w.y;
                        h[j4 * 4 + 2] += val * w.z; h[j4 * 4 + 3] += val * w.w;
                    }
                }
            }
        }
        const float* earow = ea + (size_t)e * 32;
        #pragma unroll
        for (int k4 = 0; k4 < 8; ++k4) {
            float4 v = *(const float4*)(earow + k4 * 4);
            float vv[4] = {v.x, v.y, v.z, v.w};
            #pragma unroll
            for (int c = 0; c < 4; ++c) {
                const float4* wr = (const float4*)&sW1aB[(k4 * 4 + c) * 64];
                float val = vv[c];
                #pragma unroll
                for (int j4 = 0; j4 < 16; ++j4) {
                    float4 w = wr[j4];
                    h[j4 * 4 + 0] += val * w.x; h[j4 * 4 + 1] += val * w.y;
                    h[j4 * 4 + 2] += val * w.z; h[j4 * 4 + 3] += val * w.w;
                }
            }
        }
        #pragma unroll
        for (int j = 0; j < 64; ++j) S[j] += fmaxf(h[j], 0.f);
    }

    // ---- node MLP: acc = relu(x@W2a_top + (S@Wc)/d + bc + b2a) ----
    float inv = (d > 0) ? 1.f / (float)d : 0.f;
    float acc[64];
    #pragma unroll
    for (int j = 0; j < 64; ++j) acc[j] = (d > 0) ? sbcb2a[j] : sb2a[j];
    #pragma unroll
    for (int k = 0; k < 64; ++k) {
        float val = S[k] * inv;
        const float4* wr = (const float4*)&sWc[k * 64];
        #pragma unroll
        for (int j4 = 0; j4 < 16; ++j4) {
            float4 w = wr[j4];
            acc[j4 * 4 + 0] += val * w.x; acc[j4 * 4 + 1] += val * w.y;
            acc[j4 * 4 + 2] += val * w.z; acc[j4 * 4 + 3] += val * w.w;
        }
    }
    const float* xrow = x + (size_t)i * 32;
    #pragma unroll
    for (int k4 = 0; k4 < 8; ++k4) {
        float4 v = *(const float4*)(xrow + k4 * 4);
        float vv[4] = {v.x, v.y, v.z, v.w};
        #pragma unroll
        for (int c = 0; c < 4; ++c) {
            const float4* wr = (const float4*)&sW2ax[(k4 * 4 + c) * 64];
            float val = vv[c];
            #pragma unroll
            for (int j4 = 0; j4 < 16; ++j4) {
                float4 w = wr[j4];
                acc[j4 * 4 + 0] += val * w.x; acc[j4 * 4 + 1] += val * w.y;
                acc[j4 * 4 + 2] += val * w.z; acc[j4 * 4 + 3] += val * w.w;
            }
        }
    }
    #pragma unroll
    for (int j = 0; j < 64; ++j) acc[j] = fmaxf(acc[j], 0.f);

    float o[32];
    #pragma unroll
    for (int j = 0; j < 32; ++j) o[j] = sb2b[j];
    #pragma unroll
    for (int k = 0; k < 64; ++k) {
        float val = acc[k];
        const float4* wr = (const float4*)&sW2b[k * 32];
        #pragma unroll
        for (int j4 = 0; j4 < 8; ++j4) {
            float4 w = wr[j4];
            o[j4 * 4 + 0] += val * w.x; o[j4 * 4 + 1] += val * w.y;
            o[j4 * 4 + 2] += val * w.z; o[j4 * 4 + 3] += val * w.w;
        }
    }
    float4* orow = (float4*)(out + (size_t)i * 32);
    #pragma unroll
    for (int q = 0; q < 8; ++q)
        orow[q] = make_float4(o[q * 4], o[q * 4 + 1], o[q * 4 + 2], o[q * 4 + 3]);
}

extern "C" void kernel_launch(void* const* d_in, const int* in_sizes, int n_in,
                              void* d_out, int out_size, void* d_ws, size_t ws_size,
                              hipStream_t stream) {
    const float* x   = (const float*)d_in[0];
    const int*   ei  = (const int*)d_in[1];
    const float* ea  = (const float*)d_in[2];
    const float* W1a = (const float*)d_in[5];
    const float* b1a = (const float*)d_in[6];
    const float* W1b = (const float*)d_in[7];
    const float* b1b = (const float*)d_in[8];
    const float* W2a = (const float*)d_in[9];
    const float* b2a = (const float*)d_in[10];
    const float* W2b = (const float*)d_in[11];
    const float* b2b = (const float*)d_in[12];
    float* out = (float*)d_out;

    // workspace layout
    int* wi      = (int*)d_ws;
    int* deg     = wi;                 // [N]
    int* cursor  = wi + NN;            // [N]
    int* offs    = wi + 2 * NN;        // [N]
    int* bsums   = wi + 3 * NN;        // [512]
    int* sorted  = wi + 3 * NN + 512;  // [E]
    float* wf    = (float*)(sorted + NE);
    float* Wc    = wf;                 // [4096]
    float* bc    = wf + 4096;          // [64]
    float* xa    = bc + 64;            // [N*64] optional

    size_t need_base = ((size_t)(3 * NN + 512 + NE) + 4096 + 64) * 4;
    size_t need_xa   = need_base + (size_t)NN * 64 * 4;
    bool use_xa = (ws_size >= need_xa);

    hipMemsetAsync(deg, 0, (size_t)2 * NN * sizeof(int), stream);  // deg + cursor

    dim3 blk(256);
    hipLaunchKernelGGL(k_hist, dim3((NE + 255) / 256), blk, 0, stream, ei, deg, NE);
    hipLaunchKernelGGL(k_scan1, dim3(NB), blk, 0, stream, deg, offs, bsums, NN);
    hipLaunchKernelGGL(k_scan2, dim3(1), dim3(512), 0, stream, bsums, NB);
    hipLaunchKernelGGL(k_scan3, dim3(NB), blk, 0, stream, offs, bsums, NN);
    hipLaunchKernelGGL(k_scatter, dim3((NE + 255) / 256), blk, 0, stream, ei, offs, cursor, sorted, NE);
    hipLaunchKernelGGL(k_prep, dim3(16), blk, 0, stream, W1b, b1b, W2a, Wc, bc);

    if (use_xa) {
        hipLaunchKernelGGL(k_xa, dim3(NB), blk, 0, stream, x, W1a, b1a, xa, NN);
        hipLaunchKernelGGL(k_fused<1>, dim3(NB), blk, 0, stream,
                           x, ei, ea, xa, W1a, b1a, Wc, bc, W2a, b2a, W2b, b2b,
                           deg, offs, sorted, out, NN);
    } else {
        hipLaunchKernelGGL(k_fused<0>, dim3(NB), blk, 0, stream,
                           x, ei, ea, (const float*)nullptr, W1a, b1a, Wc, bc, W2a, b2a, W2b, b2b,
                           deg, offs, sorted, out, NN);
    }
}

// Round 3
// 11151.467 us; speedup vs baseline: 1.0394x; 1.0394x over previous
//
#include <hip/hip_runtime.h>

#define NN 100000
#define NE 1600000
#define NB ((NN + 255) / 256)   // 391 blocks over nodes

// ---------------- CSR build ----------------
__global__ __launch_bounds__(256) void k_hist(const int* __restrict__ ei, int* __restrict__ deg, int E) {
    int e = blockIdx.x * 256 + threadIdx.x;
    if (e < E) atomicAdd(&deg[ei[e]], 1);
}

__global__ __launch_bounds__(256) void k_scan1(const int* __restrict__ deg, int* __restrict__ offs,
                                               int* __restrict__ bsums, int n) {
    __shared__ int s[256];
    int tid = threadIdx.x;
    int i = blockIdx.x * 256 + tid;
    int v = (i < n) ? deg[i] : 0;
    int acc = v;
    s[tid] = acc;
    __syncthreads();
    #pragma unroll
    for (int off = 1; off < 256; off <<= 1) {
        int t = (tid >= off) ? s[tid - off] : 0;
        __syncthreads();
        acc += t;
        s[tid] = acc;
        __syncthreads();
    }
    if (i < n) offs[i] = acc - v;
    if (tid == 255) bsums[blockIdx.x] = acc;
}

__global__ __launch_bounds__(512) void k_scan2(int* __restrict__ bsums, int nb) {
    __shared__ int s[512];
    int tid = threadIdx.x;
    int v = (tid < nb) ? bsums[tid] : 0;
    int acc = v;
    s[tid] = acc;
    __syncthreads();
    #pragma unroll
    for (int off = 1; off < 512; off <<= 1) {
        int t = (tid >= off) ? s[tid - off] : 0;
        __syncthreads();
        acc += t;
        s[tid] = acc;
        __syncthreads();
    }
    bsums[tid] = acc - v;
}

__global__ __launch_bounds__(256) void k_scan3(int* __restrict__ offs, const int* __restrict__ bsums, int n) {
    int i = blockIdx.x * 256 + threadIdx.x;
    if (i < n) offs[i] += bsums[blockIdx.x];
}

__global__ __launch_bounds__(256) void k_scatter(const int* __restrict__ ei, const int* __restrict__ offs,
                                                 int* __restrict__ cursor, int* __restrict__ sorted, int E) {
    int e = blockIdx.x * 256 + threadIdx.x;
    if (e >= E) return;
    int r = ei[e];
    int p = offs[r] + atomicAdd(&cursor[r], 1);
    sorted[p] = e;
}

// ---------------- precompute Wc = W1b @ W2a[32:96], bc = b1b @ W2a[32:96] ----------------
__global__ __launch_bounds__(256) void k_prep(const float* __restrict__ W1b, const float* __restrict__ b1b,
                                              const float* __restrict__ W2a,
                                              float* __restrict__ Wc, float* __restrict__ bc) {
    int t = blockIdx.x * 256 + threadIdx.x;  // 0..4095
    int r = t >> 6, c = t & 63;
    float a = 0.f;
    for (int k = 0; k < 64; ++k) a += W1b[r * 64 + k] * W2a[(32 + k) * 64 + c];
    Wc[t] = a;
    if (t < 64) {
        float bacc = 0.f;
        for (int k = 0; k < 64; ++k) bacc += b1b[k] * W2a[(32 + k) * 64 + t];
        bc[t] = bacc;
    }
}

// ---------------- precompute xa = x @ W1a[0:32] + b1a ----------------
__global__ __launch_bounds__(256) void k_xa(const float* __restrict__ x, const float* __restrict__ W1a,
                                            const float* __restrict__ b1a, float* __restrict__ xa, int N) {
    __shared__ float sW[32 * 64];
    __shared__ float sb[64];
    for (int i = threadIdx.x; i < 32 * 64; i += 256) sW[i] = W1a[i];
    if (threadIdx.x < 64) sb[threadIdx.x] = b1a[threadIdx.x];
    __syncthreads();
    int i = blockIdx.x * 256 + threadIdx.x;
    if (i >= N) return;
    float h[64];
    #pragma unroll
    for (int j = 0; j < 64; ++j) h[j] = sb[j];
    const float* xrow = x + (size_t)i * 32;
    #pragma unroll
    for (int k4 = 0; k4 < 8; ++k4) {
        float4 v = *(const float4*)(xrow + k4 * 4);
        float vv[4] = {v.x, v.y, v.z, v.w};
        #pragma unroll
        for (int c = 0; c < 4; ++c) {
            const float4* wr = (const float4*)&sW[(k4 * 4 + c) * 64];
            float val = vv[c];
            #pragma unroll
            for (int j4 = 0; j4 < 16; ++j4) {
                float4 w = wr[j4];
                h[j4 * 4 + 0] += val * w.x; h[j4 * 4 + 1] += val * w.y;
                h[j4 * 4 + 2] += val * w.z; h[j4 * 4 + 3] += val * w.w;
            }
        }
    }
    float4* xap = (float4*)(xa + (size_t)i * 64);
    #pragma unroll
    for (int q = 0; q < 16; ++q)
        xap[q] = make_float4(h[q * 4], h[q * 4 + 1], h[q * 4 + 2], h[q * 4 + 3]);
}

// ---------------- fused per-node, channel-split to cap register pressure ----------------
__global__ __launch_bounds__(256) void k_fused2(
    const float* __restrict__ x, const int* __restrict__ ei, const float* __restrict__ ea,
    const float* __restrict__ xa,
    const float* __restrict__ Wc, const float* __restrict__ bc,
    const float* __restrict__ W1a,
    const float* __restrict__ b2a, const float* __restrict__ W2a,
    const float* __restrict__ W2b, const float* __restrict__ b2b,
    const int* __restrict__ deg, const int* __restrict__ offs, const int* __restrict__ sorted,
    float* __restrict__ out, int N)
{
    __shared__ float sW1aB[32 * 64];   // W1a rows 32..63 (edge_attr part)   8KB
    __shared__ float sWc[64 * 64];     // folded W1b@W2a_bot                16KB
    __shared__ float sW2ax[32 * 64];   // W2a rows 0..31 (x part)            8KB
    __shared__ float sW2b[64 * 32];    //                                    8KB
    __shared__ float sbcb2a[64];       // bc + b2a   (d>0 case)
    __shared__ float sb2a[64];         // b2a        (d==0 case)
    __shared__ float sb2b[32];
    for (int t = threadIdx.x; t < 32 * 64; t += 256) {
        sW1aB[t] = W1a[32 * 64 + t];
        sW2ax[t] = W2a[t];
    }
    for (int t = threadIdx.x; t < 64 * 64; t += 256) sWc[t] = Wc[t];
    for (int t = threadIdx.x; t < 64 * 32; t += 256) sW2b[t] = W2b[t];
    if (threadIdx.x < 64) {
        sbcb2a[threadIdx.x] = bc[threadIdx.x] + b2a[threadIdx.x];
        sb2a[threadIdx.x] = b2a[threadIdx.x];
    }
    if (threadIdx.x < 32) sb2b[threadIdx.x] = b2b[threadIdx.x];
    __syncthreads();

    int i = blockIdx.x * 256 + threadIdx.x;
    if (i >= N) return;
    int d = deg[i], start = offs[i];
    const int* __restrict__ slist = sorted + start;
    const int* __restrict__ eicol = ei + NE;

    float S0[32], S1[32];
    #pragma unroll
    for (int j = 0; j < 32; ++j) { S0[j] = 0.f; S1[j] = 0.f; }

    #pragma unroll 1
    for (int kk = 0; kk < d; ++kk) {
        int e = slist[kk];
        int col = eicol[e];
        const float4* __restrict__ eap = (const float4*)(ea + (size_t)e * 32);
        const float4* __restrict__ xap = (const float4*)(xa + (size_t)col * 64);
        float4 ev[8];
        #pragma unroll
        for (int q = 0; q < 8; ++q) ev[q] = eap[q];

        // ---- channels 0..31 ----
        {
            float h[32];
            #pragma unroll
            for (int q = 0; q < 8; ++q) {
                float4 v = xap[q];
                h[q * 4 + 0] = v.x; h[q * 4 + 1] = v.y; h[q * 4 + 2] = v.z; h[q * 4 + 3] = v.w;
            }
            #pragma unroll
            for (int k4 = 0; k4 < 8; ++k4) {
                float vv[4] = {ev[k4].x, ev[k4].y, ev[k4].z, ev[k4].w};
                #pragma unroll
                for (int c = 0; c < 4; ++c) {
                    float val = vv[c];
                    const float4* wr = (const float4*)&sW1aB[(k4 * 4 + c) * 64];
                    #pragma unroll
                    for (int j4 = 0; j4 < 8; ++j4) {
                        float4 w = wr[j4];
                        h[j4 * 4 + 0] += val * w.x; h[j4 * 4 + 1] += val * w.y;
                        h[j4 * 4 + 2] += val * w.z; h[j4 * 4 + 3] += val * w.w;
                    }
                }
            }
            #pragma unroll
            for (int j = 0; j < 32; ++j) S0[j] += fmaxf(h[j], 0.f);
        }
        // ---- channels 32..63 ----
        {
            float h[32];
            #pragma unroll
            for (int q = 0; q < 8; ++q) {
                float4 v = xap[8 + q];
                h[q * 4 + 0] = v.x; h[q * 4 + 1] = v.y; h[q * 4 + 2] = v.z; h[q * 4 + 3] = v.w;
            }
            #pragma unroll
            for (int k4 = 0; k4 < 8; ++k4) {
                float vv[4] = {ev[k4].x, ev[k4].y, ev[k4].z, ev[k4].w};
                #pragma unroll
                for (int c = 0; c < 4; ++c) {
                    float val = vv[c];
                    const float4* wr = (const float4*)&sW1aB[(k4 * 4 + c) * 64 + 32];
                    #pragma unroll
                    for (int j4 = 0; j4 < 8; ++j4) {
                        float4 w = wr[j4];
                        h[j4 * 4 + 0] += val * w.x; h[j4 * 4 + 1] += val * w.y;
                        h[j4 * 4 + 2] += val * w.z; h[j4 * 4 + 3] += val * w.w;
                    }
                }
            }
            #pragma unroll
            for (int j = 0; j < 32; ++j) S1[j] += fmaxf(h[j], 0.f);
        }
    }

    // ---- node MLP: acc = relu(x@W2a_top + mean@Wc + bc + b2a) ----
    float inv = (d > 0) ? 1.f / (float)d : 0.f;
    #pragma unroll
    for (int j = 0; j < 32; ++j) { S0[j] *= inv; S1[j] *= inv; }

    float acc0[32], acc1[32];
    #pragma unroll
    for (int j = 0; j < 32; ++j) {
        acc0[j] = (d > 0) ? sbcb2a[j] : sb2a[j];
        acc1[j] = (d > 0) ? sbcb2a[32 + j] : sb2a[32 + j];
    }
    #pragma unroll
    for (int k = 0; k < 32; ++k) {
        float val = S0[k];
        const float4* wr = (const float4*)&sWc[k * 64];
        #pragma unroll
        for (int j4 = 0; j4 < 8; ++j4) {
            float4 w0 = wr[j4], w1 = wr[8 + j4];
            acc0[j4 * 4 + 0] += val * w0.x; acc0[j4 * 4 + 1] += val * w0.y;
            acc0[j4 * 4 + 2] += val * w0.z; acc0[j4 * 4 + 3] += val * w0.w;
            acc1[j4 * 4 + 0] += val * w1.x; acc1[j4 * 4 + 1] += val * w1.y;
            acc1[j4 * 4 + 2] += val * w1.z; acc1[j4 * 4 + 3] += val * w1.w;
        }
    }
    #pragma unroll
    for (int k = 0; k < 32; ++k) {
        float val = S1[k];
        const float4* wr = (const float4*)&sWc[(32 + k) * 64];
        #pragma unroll
        for (int j4 = 0; j4 < 8; ++j4) {
            float4 w0 = wr[j4], w1 = wr[8 + j4];
            acc0[j4 * 4 + 0] += val * w0.x; acc0[j4 * 4 + 1] += val * w0.y;
            acc0[j4 * 4 + 2] += val * w0.z; acc0[j4 * 4 + 3] += val * w0.w;
            acc1[j4 * 4 + 0] += val * w1.x; acc1[j4 * 4 + 1] += val * w1.y;
            acc1[j4 * 4 + 2] += val * w1.z; acc1[j4 * 4 + 3] += val * w1.w;
        }
    }
    const float4* __restrict__ xrp = (const float4*)(x + (size_t)i * 32);
    #pragma unroll
    for (int k4 = 0; k4 < 8; ++k4) {
        float4 v = xrp[k4];
        float vv[4] = {v.x, v.y, v.z, v.w};
        #pragma unroll
        for (int c = 0; c < 4; ++c) {
            float val = vv[c];
            const float4* wr = (const float4*)&sW2ax[(k4 * 4 + c) * 64];
            #pragma unroll
            for (int j4 = 0; j4 < 8; ++j4) {
                float4 w0 = wr[j4], w1 = wr[8 + j4];
                acc0[j4 * 4 + 0] += val * w0.x; acc0[j4 * 4 + 1] += val * w0.y;
                acc0[j4 * 4 + 2] += val * w0.z; acc0[j4 * 4 + 3] += val * w0.w;
                acc1[j4 * 4 + 0] += val * w1.x; acc1[j4 * 4 + 1] += val * w1.y;
                acc1[j4 * 4 + 2] += val * w1.z; acc1[j4 * 4 + 3] += val * w1.w;
            }
        }
    }
    #pragma unroll
    for (int j = 0; j < 32; ++j) {
        acc0[j] = fmaxf(acc0[j], 0.f);
        acc1[j] = fmaxf(acc1[j], 0.f);
    }

    float o[32];
    #pragma unroll
    for (int j = 0; j < 32; ++j) o[j] = sb2b[j];
    #pragma unroll
    for (int k = 0; k < 32; ++k) {
        float val = acc0[k];
        const float4* wr = (const float4*)&sW2b[k * 32];
        #pragma unroll
        for (int j4 = 0; j4 < 8; ++j4) {
            float4 w = wr[j4];
            o[j4 * 4 + 0] += val * w.x; o[j4 * 4 + 1] += val * w.y;
            o[j4 * 4 + 2] += val * w.z; o[j4 * 4 + 3] += val * w.w;
        }
    }
    #pragma unroll
    for (int k = 0; k < 32; ++k) {
        float val = acc1[k];
        const float4* wr = (const float4*)&sW2b[(32 + k) * 32];
        #pragma unroll
        for (int j4 = 0; j4 < 8; ++j4) {
            float4 w = wr[j4];
            o[j4 * 4 + 0] += val * w.x; o[j4 * 4 + 1] += val * w.y;
            o[j4 * 4 + 2] += val * w.z; o[j4 * 4 + 3] += val * w.w;
        }
    }
    float4* orow = (float4*)(out + (size_t)i * 32);
    #pragma unroll
    for (int q = 0; q < 8; ++q)
        orow[q] = make_float4(o[q * 4], o[q * 4 + 1], o[q * 4 + 2], o[q * 4 + 3]);
}

extern "C" void kernel_launch(void* const* d_in, const int* in_sizes, int n_in,
                              void* d_out, int out_size, void* d_ws, size_t ws_size,
                              hipStream_t stream) {
    const float* x   = (const float*)d_in[0];
    const int*   ei  = (const int*)d_in[1];
    const float* ea  = (const float*)d_in[2];
    const float* W1a = (const float*)d_in[5];
    const float* b1a = (const float*)d_in[6];
    const float* W1b = (const float*)d_in[7];
    const float* b1b = (const float*)d_in[8];
    const float* W2a = (const float*)d_in[9];
    const float* b2a = (const float*)d_in[10];
    const float* W2b = (const float*)d_in[11];
    const float* b2b = (const float*)d_in[12];
    float* out = (float*)d_out;

    // workspace layout
    int* wi      = (int*)d_ws;
    int* deg     = wi;                 // [N]
    int* cursor  = wi + NN;            // [N]
    int* offs    = wi + 2 * NN;        // [N]
    int* bsums   = wi + 3 * NN;        // [512]
    int* sorted  = wi + 3 * NN + 512;  // [E]
    float* wf    = (float*)(sorted + NE);
    float* Wc    = wf;                 // [4096]
    float* bc    = wf + 4096;          // [64]
    float* xa    = bc + 64;            // [N*64]

    hipMemsetAsync(deg, 0, (size_t)2 * NN * sizeof(int), stream);  // deg + cursor

    dim3 blk(256);
    hipLaunchKernelGGL(k_hist, dim3((NE + 255) / 256), blk, 0, stream, ei, deg, NE);
    hipLaunchKernelGGL(k_scan1, dim3(NB), blk, 0, stream, deg, offs, bsums, NN);
    hipLaunchKernelGGL(k_scan2, dim3(1), dim3(512), 0, stream, bsums, NB);
    hipLaunchKernelGGL(k_scan3, dim3(NB), blk, 0, stream, offs, bsums, NN);
    hipLaunchKernelGGL(k_scatter, dim3((NE + 255) / 256), blk, 0, stream, ei, offs, cursor, sorted, NE);
    hipLaunchKernelGGL(k_prep, dim3(16), blk, 0, stream, W1b, b1b, W2a, Wc, bc);
    hipLaunchKernelGGL(k_xa, dim3(NB), blk, 0, stream, x, W1a, b1a, xa, NN);

    hipLaunchKernelGGL(k_fused2, dim3(NB), blk, 0, stream,
                       x, ei, ea, xa, Wc, bc, W1a, b2a, W2a, W2b, b2b,
                       deg, offs, sorted, out, NN);
}

// Round 4
// 667.244 us; speedup vs baseline: 17.3708x; 16.7127x over previous
//
#include <hip/hip_runtime.h>

#define NN 100000
#define NE 1600000
#define NB ((NN + 255) / 256)

typedef unsigned int uint32;
typedef unsigned short ushort16;

__device__ __forceinline__ float bflo(uint32 u) { return __uint_as_float(u << 16); }
__device__ __forceinline__ float bfhi(uint32 u) { return __uint_as_float(u & 0xffff0000u); }
__device__ __forceinline__ uint32 bfbits(float v) { return (__float_as_uint(v) + 0x8000u) >> 16; }
__device__ __forceinline__ uint32 pack2(float a, float b) { return bfbits(a) | (bfbits(b) << 16); }

// ---------------- CSR build ----------------
__global__ __launch_bounds__(256) void k_hist(const int* __restrict__ ei, int* __restrict__ deg, int E) {
    int e = blockIdx.x * 256 + threadIdx.x;
    if (e < E) atomicAdd(&deg[ei[e]], 1);
}

__global__ __launch_bounds__(256) void k_scan1(const int* __restrict__ deg, int* __restrict__ offs,
                                               int* __restrict__ bsums, int n) {
    __shared__ int s[256];
    int tid = threadIdx.x;
    int i = blockIdx.x * 256 + tid;
    int v = (i < n) ? deg[i] : 0;
    int acc = v;
    s[tid] = acc;
    __syncthreads();
    #pragma unroll
    for (int off = 1; off < 256; off <<= 1) {
        int t = (tid >= off) ? s[tid - off] : 0;
        __syncthreads();
        acc += t;
        s[tid] = acc;
        __syncthreads();
    }
    if (i < n) offs[i] = acc - v;
    if (tid == 255) bsums[blockIdx.x] = acc;
}

__global__ __launch_bounds__(512) void k_scan2(int* __restrict__ bsums, int nb) {
    __shared__ int s[512];
    int tid = threadIdx.x;
    int v = (tid < nb) ? bsums[tid] : 0;
    int acc = v;
    s[tid] = acc;
    __syncthreads();
    #pragma unroll
    for (int off = 1; off < 512; off <<= 1) {
        int t = (tid >= off) ? s[tid - off] : 0;
        __syncthreads();
        acc += t;
        s[tid] = acc;
        __syncthreads();
    }
    bsums[tid] = acc - v;
}

__global__ __launch_bounds__(256) void k_scan3(int* __restrict__ offs, const int* __restrict__ bsums, int n) {
    int i = blockIdx.x * 256 + threadIdx.x;
    if (i < n) offs[i] += bsums[blockIdx.x];
}

__global__ __launch_bounds__(256) void k_scatter(const int* __restrict__ ei, const int* __restrict__ offs,
                                                 int* __restrict__ cursor, int* __restrict__ sorted, int E) {
    int e = blockIdx.x * 256 + threadIdx.x;
    if (e >= E) return;
    int r = ei[e];
    int p = offs[r] + atomicAdd(&cursor[r], 1);
    sorted[p] = e;
}

// ---------------- Wc = W1b @ W2a[32:96], bc = b1b @ W2a[32:96] ----------------
__global__ __launch_bounds__(256) void k_prep(const float* __restrict__ W1b, const float* __restrict__ b1b,
                                              const float* __restrict__ W2a,
                                              float* __restrict__ Wc, float* __restrict__ bc) {
    int t = blockIdx.x * 256 + threadIdx.x;  // 0..4095
    int r = t >> 6, c = t & 63;
    float a = 0.f;
    for (int k = 0; k < 64; ++k) a += W1b[r * 64 + k] * W2a[(32 + k) * 64 + c];
    Wc[t] = a;
    if (t < 64) {
        float bacc = 0.f;
        for (int k = 0; k < 64; ++k) bacc += b1b[k] * W2a[(32 + k) * 64 + t];
        bc[t] = bacc;
    }
}

// ---------------- xa = bf16(x @ W1a[0:32] + b1a) ----------------
__global__ __launch_bounds__(256) void k_xa(const float* __restrict__ x, const float* __restrict__ W1a,
                                            const float* __restrict__ b1a, ushort16* __restrict__ xa, int N) {
    __shared__ float sW[32 * 64];
    __shared__ float sb[64];
    for (int t = threadIdx.x; t < 32 * 64; t += 256) sW[t] = W1a[t];
    if (threadIdx.x < 64) sb[threadIdx.x] = b1a[threadIdx.x];
    __syncthreads();
    int i = blockIdx.x * 256 + threadIdx.x;
    if (i >= N) return;
    float h[64];
    #pragma unroll
    for (int j = 0; j < 64; ++j) h[j] = sb[j];
    const float4* xrow = (const float4*)(x + (size_t)i * 32);
    #pragma unroll
    for (int k4 = 0; k4 < 8; ++k4) {
        float4 v = xrow[k4];
        float vv[4] = {v.x, v.y, v.z, v.w};
        #pragma unroll
        for (int c = 0; c < 4; ++c) {
            const float4* wr = (const float4*)&sW[(k4 * 4 + c) * 64];
            float val = vv[c];
            #pragma unroll
            for (int j4 = 0; j4 < 16; ++j4) {
                float4 w = wr[j4];
                h[j4 * 4 + 0] += val * w.x; h[j4 * 4 + 1] += val * w.y;
                h[j4 * 4 + 2] += val * w.z; h[j4 * 4 + 3] += val * w.w;
            }
        }
    }
    uint4* xap = (uint4*)(xa + (size_t)i * 64);
    #pragma unroll
    for (int q = 0; q < 8; ++q) {
        uint4 t;
        t.x = pack2(h[q * 8 + 0], h[q * 8 + 1]);
        t.y = pack2(h[q * 8 + 2], h[q * 8 + 3]);
        t.z = pack2(h[q * 8 + 4], h[q * 8 + 5]);
        t.w = pack2(h[q * 8 + 6], h[q * 8 + 7]);
        xap[q] = t;
    }
}

// ---------------- per-edge: g = bf16(relu(xa[col] + ea @ W1a[32:64])) ----------------
__global__ __launch_bounds__(256) void k_edge(
    const int* __restrict__ ei, const float* __restrict__ ea, const ushort16* __restrict__ xa,
    const float* __restrict__ W1a, ushort16* __restrict__ g, int e0, int e1)
{
    __shared__ float sW[32 * 64];
    for (int t = threadIdx.x; t < 32 * 64; t += 256) sW[t] = W1a[32 * 64 + t];
    __syncthreads();
    int e = e0 + blockIdx.x * 256 + threadIdx.x;
    if (e >= e1) return;
    int col = ei[NE + e];

    float h[64];
    const uint4* xap = (const uint4*)(xa + (size_t)col * 64);
    #pragma unroll
    for (int q = 0; q < 8; ++q) {
        uint4 u = xap[q];
        h[q * 8 + 0] = bflo(u.x); h[q * 8 + 1] = bfhi(u.x);
        h[q * 8 + 2] = bflo(u.y); h[q * 8 + 3] = bfhi(u.y);
        h[q * 8 + 4] = bflo(u.z); h[q * 8 + 5] = bfhi(u.z);
        h[q * 8 + 6] = bflo(u.w); h[q * 8 + 7] = bfhi(u.w);
    }
    const float4* earow = (const float4*)(ea + (size_t)e * 32);
    #pragma unroll
    for (int k4 = 0; k4 < 8; ++k4) {
        float4 v = earow[k4];
        float vv[4] = {v.x, v.y, v.z, v.w};
        #pragma unroll
        for (int c = 0; c < 4; ++c) {
            float val = vv[c];
            const float4* wr = (const float4*)&sW[(k4 * 4 + c) * 64];
            #pragma unroll
            for (int j4 = 0; j4 < 16; ++j4) {
                float4 w = wr[j4];
                h[j4 * 4 + 0] += val * w.x; h[j4 * 4 + 1] += val * w.y;
                h[j4 * 4 + 2] += val * w.z; h[j4 * 4 + 3] += val * w.w;
            }
        }
    }
    uint4* gp = (uint4*)(g + (size_t)(e - e0) * 64);
    #pragma unroll
    for (int q = 0; q < 8; ++q) {
        uint4 t;
        t.x = pack2(fmaxf(h[q * 8 + 0], 0.f), fmaxf(h[q * 8 + 1], 0.f));
        t.y = pack2(fmaxf(h[q * 8 + 2], 0.f), fmaxf(h[q * 8 + 3], 0.f));
        t.z = pack2(fmaxf(h[q * 8 + 4], 0.f), fmaxf(h[q * 8 + 5], 0.f));
        t.w = pack2(fmaxf(h[q * 8 + 6], 0.f), fmaxf(h[q * 8 + 7], 0.f));
        gp[q] = t;
    }
}

// ---------------- segment sum: wave per node, lane = channel ----------------
__global__ __launch_bounds__(256) void k_seg(
    const int* __restrict__ deg, const int* __restrict__ offs, const int* __restrict__ sorted,
    const ushort16* __restrict__ g, float* __restrict__ Sacc, int e0, int e1, int first)
{
    int node = blockIdx.x * 4 + (threadIdx.x >> 6);
    int lane = threadIdx.x & 63;
    if (node >= NN) return;
    int d = deg[node], start = offs[node];
    float S = first ? 0.f : Sacc[(size_t)node * 64 + lane];
    for (int k = 0; k < d; ++k) {
        int e = sorted[start + k];
        if (e >= e0 && e < e1) {
            ushort16 u = g[(size_t)(e - e0) * 64 + lane];
            S += __uint_as_float(((uint32)u) << 16);
        }
    }
    Sacc[(size_t)node * 64 + lane] = S;
}

// ---------------- fallback: per-edge atomic scatter into Sacc ----------------
template <int USE_XA>
__global__ __launch_bounds__(256) void k_edge_atom(
    const float* __restrict__ x, const int* __restrict__ ei, const float* __restrict__ ea,
    const ushort16* __restrict__ xa,
    const float* __restrict__ W1a, const float* __restrict__ b1a,
    float* __restrict__ Sacc, int E)
{
    __shared__ float sWB[32 * 64];
    __shared__ float sWA[USE_XA ? 4 : 32 * 64];
    __shared__ float sb[64];
    for (int t = threadIdx.x; t < 32 * 64; t += 256) {
        sWB[t] = W1a[32 * 64 + t];
        if (!USE_XA) sWA[t] = W1a[t];
    }
    if (threadIdx.x < 64) sb[threadIdx.x] = b1a[threadIdx.x];
    __syncthreads();
    int e = blockIdx.x * 256 + threadIdx.x;
    if (e >= E) return;
    int row = ei[e];
    int col = ei[NE + e];

    float h[64];
    if (USE_XA) {
        const uint4* xap = (const uint4*)(xa + (size_t)col * 64);
        #pragma unroll
        for (int q = 0; q < 8; ++q) {
            uint4 u = xap[q];
            h[q * 8 + 0] = bflo(u.x); h[q * 8 + 1] = bfhi(u.x);
            h[q * 8 + 2] = bflo(u.y); h[q * 8 + 3] = bfhi(u.y);
            h[q * 8 + 4] = bflo(u.z); h[q * 8 + 5] = bfhi(u.z);
            h[q * 8 + 6] = bflo(u.w); h[q * 8 + 7] = bfhi(u.w);
        }
    } else {
        #pragma unroll
        for (int j = 0; j < 64; ++j) h[j] = sb[j];
        const float4* xrow = (const float4*)(x + (size_t)col * 32);
        #pragma unroll
        for (int k4 = 0; k4 < 8; ++k4) {
            float4 v = xrow[k4];
            float vv[4] = {v.x, v.y, v.z, v.w};
            #pragma unroll
            for (int c = 0; c < 4; ++c) {
                float val = vv[c];
                const float4* wr = (const float4*)&sWA[(k4 * 4 + c) * 64];
                #pragma unroll
                for (int j4 = 0; j4 < 16; ++j4) {
                    float4 w = wr[j4];
                    h[j4 * 4 + 0] += val * w.x; h[j4 * 4 + 1] += val * w.y;
                    h[j4 * 4 + 2] += val * w.z; h[j4 * 4 + 3] += val * w.w;
                }
            }
        }
    }
    const float4* earow = (const float4*)(ea + (size_t)e * 32);
    #pragma unroll
    for (int k4 = 0; k4 < 8; ++k4) {
        float4 v = earow[k4];
        float vv[4] = {v.x, v.y, v.z, v.w};
        #pragma unroll
        for (int c = 0; c < 4; ++c) {
            float val = vv[c];
            const float4* wr = (const float4*)&sWB[(k4 * 4 + c) * 64];
            #pragma unroll
            for (int j4 = 0; j4 < 16; ++j4) {
                float4 w = wr[j4];
                h[j4 * 4 + 0] += val * w.x; h[j4 * 4 + 1] += val * w.y;
                h[j4 * 4 + 2] += val * w.z; h[j4 * 4 + 3] += val * w.w;
            }
        }
    }
    float* srow = Sacc + (size_t)row * 64;
    #pragma unroll
    for (int j = 0; j < 64; ++j) atomicAdd(&srow[j], fmaxf(h[j], 0.f));
}

// ---------------- node MLP (R0 shape): out = relu(x@W2a_top + (Sacc/d)@Wc + bc + b2a) @ W2b + b2b ----------------
__global__ __launch_bounds__(256) void k_node(
    const float* __restrict__ x, const float* __restrict__ Sacc, const int* __restrict__ deg,
    const float* __restrict__ Wc, const float* __restrict__ bc,
    const float* __restrict__ W2a, const float* __restrict__ b2a,
    const float* __restrict__ W2b, const float* __restrict__ b2b,
    float* __restrict__ out, int N)
{
    __shared__ float sWc[64 * 64];
    __shared__ float sW2ax[32 * 64];
    __shared__ float sW2b[64 * 32];
    __shared__ float sbc2[64];
    __shared__ float sb2[64];
    __shared__ float sb2b_[32];
    for (int t = threadIdx.x; t < 64 * 64; t += 256) sWc[t] = Wc[t];
    for (int t = threadIdx.x; t < 32 * 64; t += 256) sW2ax[t] = W2a[t];
    for (int t = threadIdx.x; t < 64 * 32; t += 256) sW2b[t] = W2b[t];
    if (threadIdx.x < 64) {
        sbc2[threadIdx.x] = bc[threadIdx.x] + b2a[threadIdx.x];
        sb2[threadIdx.x] = b2a[threadIdx.x];
    }
    if (threadIdx.x < 32) sb2b_[threadIdx.x] = b2b[threadIdx.x];
    __syncthreads();

    int i = blockIdx.x * 256 + threadIdx.x;
    if (i >= N) return;
    int d = deg[i];
    float inv = (d > 0) ? 1.f / (float)d : 0.f;

    float h2[64];
    #pragma unroll
    for (int j = 0; j < 64; ++j) h2[j] = (d > 0) ? sbc2[j] : sb2[j];

    const float4* sp = (const float4*)(Sacc + (size_t)i * 64);
    #pragma unroll 2
    for (int k4 = 0; k4 < 16; ++k4) {
        float4 v = sp[k4];
        float vv[4] = {v.x * inv, v.y * inv, v.z * inv, v.w * inv};
        #pragma unroll
        for (int c = 0; c < 4; ++c) {
            float val = vv[c];
            const float4* wr = (const float4*)&sWc[(k4 * 4 + c) * 64];
            #pragma unroll
            for (int j4 = 0; j4 < 16; ++j4) {
                float4 w = wr[j4];
                h2[j4 * 4 + 0] += val * w.x; h2[j4 * 4 + 1] += val * w.y;
                h2[j4 * 4 + 2] += val * w.z; h2[j4 * 4 + 3] += val * w.w;
            }
        }
    }
    const float4* xrow = (const float4*)(x + (size_t)i * 32);
    #pragma unroll 2
    for (int k4 = 0; k4 < 8; ++k4) {
        float4 v = xrow[k4];
        float vv[4] = {v.x, v.y, v.z, v.w};
        #pragma unroll
        for (int c = 0; c < 4; ++c) {
            float val = vv[c];
            const float4* wr = (const float4*)&sW2ax[(k4 * 4 + c) * 64];
            #pragma unroll
            for (int j4 = 0; j4 < 16; ++j4) {
                float4 w = wr[j4];
                h2[j4 * 4 + 0] += val * w.x; h2[j4 * 4 + 1] += val * w.y;
                h2[j4 * 4 + 2] += val * w.z; h2[j4 * 4 + 3] += val * w.w;
            }
        }
    }
    #pragma unroll
    for (int j = 0; j < 64; ++j) h2[j] = fmaxf(h2[j], 0.f);

    float o[32];
    #pragma unroll
    for (int j = 0; j < 32; ++j) o[j] = sb2b_[j];
    #pragma unroll
    for (int k = 0; k < 64; ++k) {
        float val = h2[k];
        const float4* wr = (const float4*)&sW2b[k * 32];
        #pragma unroll
        for (int j4 = 0; j4 < 8; ++j4) {
            float4 w = wr[j4];
            o[j4 * 4 + 0] += val * w.x; o[j4 * 4 + 1] += val * w.y;
            o[j4 * 4 + 2] += val * w.z; o[j4 * 4 + 3] += val * w.w;
        }
    }
    float4* orow = (float4*)(out + (size_t)i * 32);
    #pragma unroll
    for (int q = 0; q < 8; ++q)
        orow[q] = make_float4(o[q * 4], o[q * 4 + 1], o[q * 4 + 2], o[q * 4 + 3]);
}

extern "C" void kernel_launch(void* const* d_in, const int* in_sizes, int n_in,
                              void* d_out, int out_size, void* d_ws, size_t ws_size,
                              hipStream_t stream) {
    const float* x   = (const float*)d_in[0];
    const int*   ei  = (const int*)d_in[1];
    const float* ea  = (const float*)d_in[2];
    const float* W1a = (const float*)d_in[5];
    const float* b1a = (const float*)d_in[6];
    const float* W1b = (const float*)d_in[7];
    const float* b1b = (const float*)d_in[8];
    const float* W2a = (const float*)d_in[9];
    const float* b2a = (const float*)d_in[10];
    const float* W2b = (const float*)d_in[11];
    const float* b2b = (const float*)d_in[12];
    float* out = (float*)d_out;

    // workspace layout (ordered so small-ws fallbacks use the prefix)
    char* p = (char*)d_ws;
    int* deg        = (int*)p;        p += (size_t)NN * 4;
    float* Wc       = (float*)p;      p += 4096 * 4;
    float* bc       = (float*)p;      p += 64 * 4;
    float* Sacc     = (float*)p;      p += (size_t)NN * 64 * 4;
    size_t off_min  = (size_t)(p - (char*)d_ws);           // ~26.0 MB
    ushort16* xa    = (ushort16*)p;   p += (size_t)NN * 64 * 2;
    size_t off_xa   = (size_t)(p - (char*)d_ws);           // ~38.8 MB
    int* cursor     = (int*)p;        p += (size_t)NN * 4;
    int* offs       = (int*)p;        p += (size_t)NN * 4;
    int* bsums      = (int*)p;        p += 512 * 4;
    int* sorted     = (int*)p;        p += (size_t)NE * 4;
    size_t off_csr  = (size_t)(p - (char*)d_ws);           // ~46.0 MB
    ushort16* g     = (ushort16*)p;

    long long availg = (ws_size > off_csr) ? (long long)(ws_size - off_csr) : 0;
    long long chunkE = availg / 128;   // 128 bytes per edge row of g
    dim3 blk(256);

    if (chunkE >= 100000) {
        // ---------- primary path: materialized g + segment sum ----------
        if (chunkE > NE) chunkE = NE;
        hipMemsetAsync(deg, 0, (size_t)NN * 4, stream);
        hipMemsetAsync(cursor, 0, (size_t)NN * 4, stream);
        hipLaunchKernelGGL(k_hist, dim3((NE + 255) / 256), blk, 0, stream, ei, deg, NE);
        hipLaunchKernelGGL(k_scan1, dim3(NB), blk, 0, stream, deg, offs, bsums, NN);
        hipLaunchKernelGGL(k_scan2, dim3(1), dim3(512), 0, stream, bsums, NB);
        hipLaunchKernelGGL(k_scan3, dim3(NB), blk, 0, stream, offs, bsums, NN);
        hipLaunchKernelGGL(k_scatter, dim3((NE + 255) / 256), blk, 0, stream, ei, offs, cursor, sorted, NE);
        hipLaunchKernelGGL(k_prep, dim3(16), blk, 0, stream, W1b, b1b, W2a, Wc, bc);
        hipLaunchKernelGGL(k_xa, dim3(NB), blk, 0, stream, x, W1a, b1a, xa, NN);

        int nch = (int)((NE + chunkE - 1) / chunkE);
        for (int c = 0; c < nch; ++c) {
            int ce0 = (int)(c * chunkE);
            int ce1 = (int)((ce0 + chunkE < NE) ? ce0 + chunkE : NE);
            hipLaunchKernelGGL(k_edge, dim3((ce1 - ce0 + 255) / 256), blk, 0, stream,
                               ei, ea, xa, W1a, g, ce0, ce1);
            hipLaunchKernelGGL(k_seg, dim3((NN + 3) / 4), blk, 0, stream,
                               deg, offs, sorted, g, Sacc, ce0, ce1, (c == 0) ? 1 : 0);
        }
        hipLaunchKernelGGL(k_node, dim3(NB), blk, 0, stream,
                           x, Sacc, deg, Wc, bc, W2a, b2a, W2b, b2b, out, NN);
    } else {
        // ---------- fallback: atomic scatter ----------
        hipMemsetAsync(deg, 0, (size_t)NN * 4, stream);
        hipMemsetAsync(Sacc, 0, (size_t)NN * 64 * 4, stream);
        hipLaunchKernelGGL(k_hist, dim3((NE + 255) / 256), blk, 0, stream, ei, deg, NE);
        hipLaunchKernelGGL(k_prep, dim3(16), blk, 0, stream, W1b, b1b, W2a, Wc, bc);
        if (ws_size >= off_xa) {
            hipLaunchKernelGGL(k_xa, dim3(NB), blk, 0, stream, x, W1a, b1a, xa, NN);
            hipLaunchKernelGGL(k_edge_atom<1>, dim3((NE + 255) / 256), blk, 0, stream,
                               x, ei, ea, xa, W1a, b1a, Sacc, NE);
        } else {
            hipLaunchKernelGGL(k_edge_atom<0>, dim3((NE + 255) / 256), blk, 0, stream,
                               x, ei, ea, (const ushort16*)nullptr, W1a, b1a, Sacc, NE);
        }
        hipLaunchKernelGGL(k_node, dim3(NB), blk, 0, stream,
                           x, Sacc, deg, Wc, bc, W2a, b2a, W2b, b2b, out, NN);
    }
}

// Round 5
// 424.561 us; speedup vs baseline: 27.3001x; 1.5716x over previous
//
#include <hip/hip_runtime.h>

#define NN 100000
#define NE 1600000
#define NB ((NN + 255) / 256)
#define TPW 8   // tiles (of 16 edges) per wave in k_edge_mfma

typedef unsigned int uint32;
typedef unsigned short ushort16;
typedef float f32x4 __attribute__((ext_vector_type(4)));
typedef short bf16x8 __attribute__((ext_vector_type(8)));

__device__ __forceinline__ float bflo(uint32 u) { return __uint_as_float(u << 16); }
__device__ __forceinline__ float bfhi(uint32 u) { return __uint_as_float(u & 0xffff0000u); }
__device__ __forceinline__ uint32 bfbits(float v) { return (__float_as_uint(v) + 0x8000u) >> 16; }
__device__ __forceinline__ uint32 pack2(float a, float b) { return bfbits(a) | (bfbits(b) << 16); }

// ---------------- CSR build ----------------
__global__ __launch_bounds__(256) void k_hist(const int* __restrict__ ei, int* __restrict__ deg, int E) {
    int e = blockIdx.x * 256 + threadIdx.x;
    if (e < E) atomicAdd(&deg[ei[e]], 1);
}

__global__ __launch_bounds__(256) void k_scan1(const int* __restrict__ deg, int* __restrict__ offs,
                                               int* __restrict__ bsums, int n) {
    __shared__ int s[256];
    int tid = threadIdx.x;
    int i = blockIdx.x * 256 + tid;
    int v = (i < n) ? deg[i] : 0;
    int acc = v;
    s[tid] = acc;
    __syncthreads();
    #pragma unroll
    for (int off = 1; off < 256; off <<= 1) {
        int t = (tid >= off) ? s[tid - off] : 0;
        __syncthreads();
        acc += t;
        s[tid] = acc;
        __syncthreads();
    }
    if (i < n) offs[i] = acc - v;
    if (tid == 255) bsums[blockIdx.x] = acc;
}

__global__ __launch_bounds__(512) void k_scan2(int* __restrict__ bsums, int nb) {
    __shared__ int s[512];
    int tid = threadIdx.x;
    int v = (tid < nb) ? bsums[tid] : 0;
    int acc = v;
    s[tid] = acc;
    __syncthreads();
    #pragma unroll
    for (int off = 1; off < 512; off <<= 1) {
        int t = (tid >= off) ? s[tid - off] : 0;
        __syncthreads();
        acc += t;
        s[tid] = acc;
        __syncthreads();
    }
    bsums[tid] = acc - v;
}

__global__ __launch_bounds__(256) void k_scan3(int* __restrict__ offs, const int* __restrict__ bsums, int n) {
    int i = blockIdx.x * 256 + threadIdx.x;
    if (i < n) offs[i] += bsums[blockIdx.x];
}

// writes pos[e] (coalesced) = CSR slot of edge e
__global__ __launch_bounds__(256) void k_scatter_pos(const int* __restrict__ ei, const int* __restrict__ offs,
                                                     int* __restrict__ cursor, int* __restrict__ pos, int E) {
    int e = blockIdx.x * 256 + threadIdx.x;
    if (e >= E) return;
    int r = ei[e];
    pos[e] = offs[r] + atomicAdd(&cursor[r], 1);
}

// ---------------- Wc = W1b @ W2a[32:96], bc = b1b @ W2a[32:96] ----------------
__global__ __launch_bounds__(256) void k_prep(const float* __restrict__ W1b, const float* __restrict__ b1b,
                                              const float* __restrict__ W2a,
                                              float* __restrict__ Wc, float* __restrict__ bc) {
    int t = blockIdx.x * 256 + threadIdx.x;  // 0..4095
    int r = t >> 6, c = t & 63;
    float a = 0.f;
    for (int k = 0; k < 64; ++k) a += W1b[r * 64 + k] * W2a[(32 + k) * 64 + c];
    Wc[t] = a;
    if (t < 64) {
        float bacc = 0.f;
        for (int k = 0; k < 64; ++k) bacc += b1b[k] * W2a[(32 + k) * 64 + t];
        bc[t] = bacc;
    }
}

// ---------------- xa = bf16(x @ W1a[0:32] + b1a) ----------------
__global__ __launch_bounds__(256) void k_xa(const float* __restrict__ x, const float* __restrict__ W1a,
                                            const float* __restrict__ b1a, ushort16* __restrict__ xa, int N) {
    __shared__ float sW[32 * 64];
    __shared__ float sb[64];
    for (int t = threadIdx.x; t < 32 * 64; t += 256) sW[t] = W1a[t];
    if (threadIdx.x < 64) sb[threadIdx.x] = b1a[threadIdx.x];
    __syncthreads();
    int i = blockIdx.x * 256 + threadIdx.x;
    if (i >= N) return;
    float h[64];
    #pragma unroll
    for (int j = 0; j < 64; ++j) h[j] = sb[j];
    const float4* xrow = (const float4*)(x + (size_t)i * 32);
    #pragma unroll
    for (int k4 = 0; k4 < 8; ++k4) {
        float4 v = xrow[k4];
        float vv[4] = {v.x, v.y, v.z, v.w};
        #pragma unroll
        for (int c = 0; c < 4; ++c) {
            const float4* wr = (const float4*)&sW[(k4 * 4 + c) * 64];
            float val = vv[c];
            #pragma unroll
            for (int j4 = 0; j4 < 16; ++j4) {
                float4 w = wr[j4];
                h[j4 * 4 + 0] += val * w.x; h[j4 * 4 + 1] += val * w.y;
                h[j4 * 4 + 2] += val * w.z; h[j4 * 4 + 3] += val * w.w;
            }
        }
    }
    uint4* xap = (uint4*)(xa + (size_t)i * 64);
    #pragma unroll
    for (int q = 0; q < 8; ++q) {
        uint4 t;
        t.x = pack2(h[q * 8 + 0], h[q * 8 + 1]);
        t.y = pack2(h[q * 8 + 2], h[q * 8 + 3]);
        t.z = pack2(h[q * 8 + 4], h[q * 8 + 5]);
        t.w = pack2(h[q * 8 + 6], h[q * 8 + 7]);
        xap[q] = t;
    }
}

// ---------------- MFMA edge kernel: g[pos[e]] = bf16(relu(xa[col] + ea @ W1a[32:64])) ----------------
// tile = 16 edges; per tile: 4x mfma_f32_16x16x32_bf16 ([16e x 32k] @ [32k x 16ch])
// A frag: lane l -> row l&15, k = 8*(l>>4)+i ; B frag: lane l -> col l&15, same k
// D: lane l, reg r -> row (l>>4)*4+r, col l&15   (m89-verified mapping)
__global__ __launch_bounds__(256) void k_edge_mfma(
    const int* __restrict__ ei, const float* __restrict__ ea, const ushort16* __restrict__ xa,
    const float* __restrict__ W1a, const int* __restrict__ pos, ushort16* __restrict__ g)
{
    __shared__ ushort16 sWt[64 * 32];        // W1a_bot transposed [ch][k], bf16
    __shared__ float t_lds[4][64 * 17];      // per-wave D tile [ch][edge], pad 17

    for (int idx = threadIdx.x; idx < 2048; idx += 256) {
        int ch = idx & 63, k = idx >> 6;
        sWt[ch * 32 + k] = (ushort16)bfbits(W1a[(32 + k) * 64 + ch]);
    }
    __syncthreads();

    int wave = threadIdx.x >> 6;
    int lane = threadIdx.x & 63;
    int m = lane & 15;    // phase1: A row / phase2: edge-in-tile
    int qq = lane >> 4;   // phase1: k-group / phase2: channel quarter

    bf16x8 bfr[4];
    #pragma unroll
    for (int cc = 0; cc < 4; ++cc)
        bfr[cc] = *(const bf16x8*)&sWt[(cc * 16 + m) * 32 + qq * 8];

    float* tw = &t_lds[wave][0];
    int base = blockIdx.x * (64 * TPW) + wave * (16 * TPW);

    #pragma unroll 1
    for (int t = 0; t < TPW; ++t) {
        int e0 = base + t * 16;
        // ---- phase 1: MFMA ----
        const float* arow = ea + (size_t)(e0 + m) * 32 + qq * 8;
        float4 a0 = *(const float4*)arow;
        float4 a1 = *(const float4*)(arow + 4);
        union { uint4 u; bf16x8 v; } af;
        af.u.x = pack2(a0.x, a0.y);
        af.u.y = pack2(a0.z, a0.w);
        af.u.z = pack2(a1.x, a1.y);
        af.u.w = pack2(a1.z, a1.w);
        f32x4 acc[4];
        #pragma unroll
        for (int cc = 0; cc < 4; ++cc)
            acc[cc] = __builtin_amdgcn_mfma_f32_16x16x32_bf16(af.v, bfr[cc], (f32x4){0.f, 0.f, 0.f, 0.f}, 0, 0, 0);
        #pragma unroll
        for (int cc = 0; cc < 4; ++cc) {
            #pragma unroll
            for (int r = 0; r < 4; ++r)
                tw[(cc * 16 + m) * 17 + qq * 4 + r] = acc[cc][r];
        }
        __syncthreads();
        // ---- phase 2: lane = edge m, channel quarter qq ----
        int e = e0 + m;
        int col = ei[NE + e];
        int p = pos[e];
        const uint4* xap = (const uint4*)(xa + (size_t)col * 64 + qq * 16);
        uint4 xv0 = xap[0];
        uint4 xv1 = xap[1];
        float tv[16];
        #pragma unroll
        for (int j = 0; j < 16; ++j) tv[j] = tw[(qq * 16 + j) * 17 + m];
        float xf[16];
        xf[0] = bflo(xv0.x); xf[1] = bfhi(xv0.x); xf[2] = bflo(xv0.y); xf[3] = bfhi(xv0.y);
        xf[4] = bflo(xv0.z); xf[5] = bfhi(xv0.z); xf[6] = bflo(xv0.w); xf[7] = bfhi(xv0.w);
        xf[8] = bflo(xv1.x); xf[9] = bfhi(xv1.x); xf[10] = bflo(xv1.y); xf[11] = bfhi(xv1.y);
        xf[12] = bflo(xv1.z); xf[13] = bfhi(xv1.z); xf[14] = bflo(xv1.w); xf[15] = bfhi(xv1.w);
        uint4 o0, o1;
        o0.x = pack2(fmaxf(xf[0] + tv[0], 0.f), fmaxf(xf[1] + tv[1], 0.f));
        o0.y = pack2(fmaxf(xf[2] + tv[2], 0.f), fmaxf(xf[3] + tv[3], 0.f));
        o0.z = pack2(fmaxf(xf[4] + tv[4], 0.f), fmaxf(xf[5] + tv[5], 0.f));
        o0.w = pack2(fmaxf(xf[6] + tv[6], 0.f), fmaxf(xf[7] + tv[7], 0.f));
        o1.x = pack2(fmaxf(xf[8] + tv[8], 0.f), fmaxf(xf[9] + tv[9], 0.f));
        o1.y = pack2(fmaxf(xf[10] + tv[10], 0.f), fmaxf(xf[11] + tv[11], 0.f));
        o1.z = pack2(fmaxf(xf[12] + tv[12], 0.f), fmaxf(xf[13] + tv[13], 0.f));
        o1.w = pack2(fmaxf(xf[14] + tv[14], 0.f), fmaxf(xf[15] + tv[15], 0.f));
        uint4* gp = (uint4*)(g + (size_t)p * 64 + qq * 16);
        gp[0] = o0;
        gp[1] = o1;
        __syncthreads();
    }
}

// ---------------- segment sum over CONTIGUOUS g rows: wave/node, 2 rows/iter ----------------
__global__ __launch_bounds__(256) void k_seg_c(
    const int* __restrict__ deg, const int* __restrict__ offs,
    const ushort16* __restrict__ g, float* __restrict__ Sacc)
{
    int node = blockIdx.x * 4 + (threadIdx.x >> 6);
    if (node >= NN) return;
    int lane = threadIdx.x & 63;
    int half = lane >> 5;   // row parity
    int ui = lane & 31;     // uint index (2 channels)
    int d = deg[node];
    size_t start = (size_t)offs[node];
    float S0 = 0.f, S1 = 0.f;
    for (int r = half; r < d; r += 2) {
        uint32 u = ((const uint32*)(g + (start + r) * 64))[ui];
        S0 += bflo(u);
        S1 += bfhi(u);
    }
    S0 += __shfl_xor(S0, 32);
    S1 += __shfl_xor(S1, 32);
    if (half == 0) {
        float2* sp = (float2*)(Sacc + (size_t)node * 64);
        sp[ui] = make_float2(S0, S1);
    }
}

// ---------------- fallback: per-edge atomic scatter (only if ws too small; not expected) ----------------
__global__ __launch_bounds__(256) void k_edge_atom(
    const float* __restrict__ x, const int* __restrict__ ei, const float* __restrict__ ea,
    const float* __restrict__ W1a, const float* __restrict__ b1a,
    float* __restrict__ Sacc, int E)
{
    __shared__ float sWB[32 * 64];
    __shared__ float sWA[32 * 64];
    __shared__ float sb[64];
    for (int t = threadIdx.x; t < 32 * 64; t += 256) {
        sWB[t] = W1a[32 * 64 + t];
        sWA[t] = W1a[t];
    }
    if (threadIdx.x < 64) sb[threadIdx.x] = b1a[threadIdx.x];
    __syncthreads();
    int e = blockIdx.x * 256 + threadIdx.x;
    if (e >= E) return;
    int row = ei[e];
    int col = ei[NE + e];
    float h[64];
    #pragma unroll
    for (int j = 0; j < 64; ++j) h[j] = sb[j];
    const float4* xrow = (const float4*)(x + (size_t)col * 32);
    #pragma unroll
    for (int k4 = 0; k4 < 8; ++k4) {
        float4 v = xrow[k4];
        float vv[4] = {v.x, v.y, v.z, v.w};
        #pragma unroll
        for (int c = 0; c < 4; ++c) {
            float val = vv[c];
            const float4* wr = (const float4*)&sWA[(k4 * 4 + c) * 64];
            #pragma unroll
            for (int j4 = 0; j4 < 16; ++j4) {
                float4 w = wr[j4];
                h[j4 * 4 + 0] += val * w.x; h[j4 * 4 + 1] += val * w.y;
                h[j4 * 4 + 2] += val * w.z; h[j4 * 4 + 3] += val * w.w;
            }
        }
    }
    const float4* earow = (const float4*)(ea + (size_t)e * 32);
    #pragma unroll
    for (int k4 = 0; k4 < 8; ++k4) {
        float4 v = earow[k4];
        float vv[4] = {v.x, v.y, v.z, v.w};
        #pragma unroll
        for (int c = 0; c < 4; ++c) {
            float val = vv[c];
            const float4* wr = (const float4*)&sWB[(k4 * 4 + c) * 64];
            #pragma unroll
            for (int j4 = 0; j4 < 16; ++j4) {
                float4 w = wr[j4];
                h[j4 * 4 + 0] += val * w.x; h[j4 * 4 + 1] += val * w.y;
                h[j4 * 4 + 2] += val * w.z; h[j4 * 4 + 3] += val * w.w;
            }
        }
    }
    float* srow = Sacc + (size_t)row * 64;
    #pragma unroll
    for (int j = 0; j < 64; ++j) atomicAdd(&srow[j], fmaxf(h[j], 0.f));
}

// ---------------- node MLP: out = relu(x@W2a_top + (Sacc/d)@Wc + bc + b2a) @ W2b + b2b ----------------
__global__ __launch_bounds__(256) void k_node(
    const float* __restrict__ x, const float* __restrict__ Sacc, const int* __restrict__ deg,
    const float* __restrict__ Wc, const float* __restrict__ bc,
    const float* __restrict__ W2a, const float* __restrict__ b2a,
    const float* __restrict__ W2b, const float* __restrict__ b2b,
    float* __restrict__ out, int N)
{
    __shared__ float sWc[64 * 64];
    __shared__ float sW2ax[32 * 64];
    __shared__ float sW2b[64 * 32];
    __shared__ float sbc2[64];
    __shared__ float sb2[64];
    __shared__ float sb2b_[32];
    for (int t = threadIdx.x; t < 64 * 64; t += 256) sWc[t] = Wc[t];
    for (int t = threadIdx.x; t < 32 * 64; t += 256) sW2ax[t] = W2a[t];
    for (int t = threadIdx.x; t < 64 * 32; t += 256) sW2b[t] = W2b[t];
    if (threadIdx.x < 64) {
        sbc2[threadIdx.x] = bc[threadIdx.x] + b2a[threadIdx.x];
        sb2[threadIdx.x] = b2a[threadIdx.x];
    }
    if (threadIdx.x < 32) sb2b_[threadIdx.x] = b2b[threadIdx.x];
    __syncthreads();

    int i = blockIdx.x * 256 + threadIdx.x;
    if (i >= N) return;
    int d = deg[i];
    float inv = (d > 0) ? 1.f / (float)d : 0.f;

    float h2[64];
    #pragma unroll
    for (int j = 0; j < 64; ++j) h2[j] = (d > 0) ? sbc2[j] : sb2[j];

    const float4* sp = (const float4*)(Sacc + (size_t)i * 64);
    #pragma unroll 2
    for (int k4 = 0; k4 < 16; ++k4) {
        float4 v = sp[k4];
        float vv[4] = {v.x * inv, v.y * inv, v.z * inv, v.w * inv};
        #pragma unroll
        for (int c = 0; c < 4; ++c) {
            float val = vv[c];
            const float4* wr = (const float4*)&sWc[(k4 * 4 + c) * 64];
            #pragma unroll
            for (int j4 = 0; j4 < 16; ++j4) {
                float4 w = wr[j4];
                h2[j4 * 4 + 0] += val * w.x; h2[j4 * 4 + 1] += val * w.y;
                h2[j4 * 4 + 2] += val * w.z; h2[j4 * 4 + 3] += val * w.w;
            }
        }
    }
    const float4* xrow = (const float4*)(x + (size_t)i * 32);
    #pragma unroll 2
    for (int k4 = 0; k4 < 8; ++k4) {
        float4 v = xrow[k4];
        float vv[4] = {v.x, v.y, v.z, v.w};
        #pragma unroll
        for (int c = 0; c < 4; ++c) {
            float val = vv[c];
            const float4* wr = (const float4*)&sW2ax[(k4 * 4 + c) * 64];
            #pragma unroll
            for (int j4 = 0; j4 < 16; ++j4) {
                float4 w = wr[j4];
                h2[j4 * 4 + 0] += val * w.x; h2[j4 * 4 + 1] += val * w.y;
                h2[j4 * 4 + 2] += val * w.z; h2[j4 * 4 + 3] += val * w.w;
            }
        }
    }
    #pragma unroll
    for (int j = 0; j < 64; ++j) h2[j] = fmaxf(h2[j], 0.f);

    float o[32];
    #pragma unroll
    for (int j = 0; j < 32; ++j) o[j] = sb2b_[j];
    #pragma unroll
    for (int k = 0; k < 64; ++k) {
        float val = h2[k];
        const float4* wr = (const float4*)&sW2b[k * 32];
        #pragma unroll
        for (int j4 = 0; j4 < 8; ++j4) {
            float4 w = wr[j4];
            o[j4 * 4 + 0] += val * w.x; o[j4 * 4 + 1] += val * w.y;
            o[j4 * 4 + 2] += val * w.z; o[j4 * 4 + 3] += val * w.w;
        }
    }
    float4* orow = (float4*)(out + (size_t)i * 32);
    #pragma unroll
    for (int q = 0; q < 8; ++q)
        orow[q] = make_float4(o[q * 4], o[q * 4 + 1], o[q * 4 + 2], o[q * 4 + 3]);
}

extern "C" void kernel_launch(void* const* d_in, const int* in_sizes, int n_in,
                              void* d_out, int out_size, void* d_ws, size_t ws_size,
                              hipStream_t stream) {
    const float* x   = (const float*)d_in[0];
    const int*   ei  = (const int*)d_in[1];
    const float* ea  = (const float*)d_in[2];
    const float* W1a = (const float*)d_in[5];
    const float* b1a = (const float*)d_in[6];
    const float* W1b = (const float*)d_in[7];
    const float* b1b = (const float*)d_in[8];
    const float* W2a = (const float*)d_in[9];
    const float* b2a = (const float*)d_in[10];
    const float* W2b = (const float*)d_in[11];
    const float* b2b = (const float*)d_in[12];
    float* out = (float*)d_out;

    // workspace layout
    char* p = (char*)d_ws;
    int* deg        = (int*)p;        p += (size_t)NN * 4;
    int* cursor     = (int*)p;        p += (size_t)NN * 4;   // adjacent to deg: single memset
    int* offs       = (int*)p;        p += (size_t)NN * 4;
    int* bsums      = (int*)p;        p += 2048;
    float* Wc       = (float*)p;      p += 4096 * 4;
    float* bc       = (float*)p;      p += 64 * 4;
    int* pos        = (int*)p;        p += (size_t)NE * 4;
    ushort16* xa    = (ushort16*)p;   p += (size_t)NN * 64 * 2;
    float* Sacc     = (float*)p;      p += (size_t)NN * 64 * 4;
    size_t off_g    = (size_t)(p - (char*)d_ws);             // ~46 MB
    ushort16* g     = (ushort16*)p;

    dim3 blk(256);
    bool primary = (ws_size >= off_g + (size_t)NE * 128);    // full g fits (R4 evidence: yes)

    if (primary) {
        hipMemsetAsync(deg, 0, (size_t)2 * NN * 4, stream);  // deg + cursor
        hipLaunchKernelGGL(k_hist, dim3((NE + 255) / 256), blk, 0, stream, ei, deg, NE);
        hipLaunchKernelGGL(k_scan1, dim3(NB), blk, 0, stream, deg, offs, bsums, NN);
        hipLaunchKernelGGL(k_scan2, dim3(1), dim3(512), 0, stream, bsums, NB);
        hipLaunchKernelGGL(k_scan3, dim3(NB), blk, 0, stream, offs, bsums, NN);
        hipLaunchKernelGGL(k_scatter_pos, dim3((NE + 255) / 256), blk, 0, stream, ei, offs, cursor, pos, NE);
        hipLaunchKernelGGL(k_prep, dim3(16), blk, 0, stream, W1b, b1b, W2a, Wc, bc);
        hipLaunchKernelGGL(k_xa, dim3(NB), blk, 0, stream, x, W1a, b1a, xa, NN);
        hipLaunchKernelGGL(k_edge_mfma, dim3(NE / (64 * TPW)), blk, 0, stream, ei, ea, xa, W1a, pos, g);
        hipLaunchKernelGGL(k_seg_c, dim3((NN + 3) / 4), blk, 0, stream, deg, offs, g, Sacc);
        hipLaunchKernelGGL(k_node, dim3(NB), blk, 0, stream,
                           x, Sacc, deg, Wc, bc, W2a, b2a, W2b, b2b, out, NN);
    } else {
        // fallback: fp32 atomic scatter (correct, slower; not expected to run)
        hipMemsetAsync(deg, 0, (size_t)NN * 4, stream);
        hipMemsetAsync(Sacc, 0, (size_t)NN * 64 * 4, stream);
        hipLaunchKernelGGL(k_hist, dim3((NE + 255) / 256), blk, 0, stream, ei, deg, NE);
        hipLaunchKernelGGL(k_prep, dim3(16), blk, 0, stream, W1b, b1b, W2a, Wc, bc);
        hipLaunchKernelGGL(k_edge_atom, dim3((NE + 255) / 256), blk, 0, stream,
                           x, ei, ea, W1a, b1a, Sacc, NE);
        hipLaunchKernelGGL(k_node, dim3(NB), blk, 0, stream,
                           x, Sacc, deg, Wc, bc, W2a, b2a, W2b, b2b, out, NN);
    }
}

// Round 6
// 420.776 us; speedup vs baseline: 27.5457x; 1.0090x over previous
//
#include <hip/hip_runtime.h>

#define NN 100000
#define NE 1600000
#define NB ((NN + 255) / 256)
#define TPW 8   // tiles (of 16 edges) per wave in k_edge_mfma

typedef unsigned int uint32;
typedef unsigned short ushort16;
typedef float f32x4 __attribute__((ext_vector_type(4)));
typedef short bf16x8 __attribute__((ext_vector_type(8)));

__device__ __forceinline__ float bflo(uint32 u) { return __uint_as_float(u << 16); }
__device__ __forceinline__ float bfhi(uint32 u) { return __uint_as_float(u & 0xffff0000u); }
__device__ __forceinline__ uint32 bfbits(float v) { return (__float_as_uint(v) + 0x8000u) >> 16; }
__device__ __forceinline__ uint32 pack2(float a, float b) { return bfbits(a) | (bfbits(b) << 16); }

// channel permutation: sigma(c) swaps cc (bits 5:4) and qq (bits 3:2) fields
__device__ __forceinline__ int sigma_ch(int c) {
    return (((c >> 2) & 3) << 4) + (((c >> 4) & 3) << 2) + (c & 3);
}

// ---------------- CSR build ----------------
__global__ __launch_bounds__(256) void k_hist(const int* __restrict__ ei, int* __restrict__ deg, int E) {
    int e = blockIdx.x * 256 + threadIdx.x;
    if (e < E) atomicAdd(&deg[ei[e]], 1);
}

__global__ __launch_bounds__(256) void k_scan1(const int* __restrict__ deg, int* __restrict__ offs,
                                               int* __restrict__ bsums, int n) {
    __shared__ int s[256];
    int tid = threadIdx.x;
    int i = blockIdx.x * 256 + tid;
    int v = (i < n) ? deg[i] : 0;
    int acc = v;
    s[tid] = acc;
    __syncthreads();
    #pragma unroll
    for (int off = 1; off < 256; off <<= 1) {
        int t = (tid >= off) ? s[tid - off] : 0;
        __syncthreads();
        acc += t;
        s[tid] = acc;
        __syncthreads();
    }
    if (i < n) offs[i] = acc - v;
    if (tid == 255) bsums[blockIdx.x] = acc;
}

__global__ __launch_bounds__(512) void k_scan2(int* __restrict__ bsums, int nb) {
    __shared__ int s[512];
    int tid = threadIdx.x;
    int v = (tid < nb) ? bsums[tid] : 0;
    int acc = v;
    s[tid] = acc;
    __syncthreads();
    #pragma unroll
    for (int off = 1; off < 512; off <<= 1) {
        int t = (tid >= off) ? s[tid - off] : 0;
        __syncthreads();
        acc += t;
        s[tid] = acc;
        __syncthreads();
    }
    bsums[tid] = acc - v;
}

__global__ __launch_bounds__(256) void k_scan3(int* __restrict__ offs, const int* __restrict__ bsums, int n) {
    int i = blockIdx.x * 256 + threadIdx.x;
    if (i < n) offs[i] += bsums[blockIdx.x];
}

// writes pos[e] (coalesced) = CSR slot of edge e
__global__ __launch_bounds__(256) void k_scatter_pos(const int* __restrict__ ei, const int* __restrict__ offs,
                                                     int* __restrict__ cursor, int* __restrict__ pos, int E) {
    int e = blockIdx.x * 256 + threadIdx.x;
    if (e >= E) return;
    int r = ei[e];
    pos[e] = offs[r] + atomicAdd(&cursor[r], 1);
}

// ---------------- Wc = W1b @ W2a[32:96] (rows stored sigma-permuted when perm=1), bc = b1b @ W2a[32:96] ----------------
__global__ __launch_bounds__(256) void k_prep(const float* __restrict__ W1b, const float* __restrict__ b1b,
                                              const float* __restrict__ W2a,
                                              float* __restrict__ Wc, float* __restrict__ bc, int perm) {
    int t = blockIdx.x * 256 + threadIdx.x;  // 0..4095
    int r = t >> 6, c = t & 63;
    float a = 0.f;
    for (int k = 0; k < 64; ++k) a += W1b[r * 64 + k] * W2a[(32 + k) * 64 + c];
    int rs = perm ? sigma_ch(r) : r;
    Wc[rs * 64 + c] = a;
    if (t < 64) {
        float bacc = 0.f;
        for (int k = 0; k < 64; ++k) bacc += b1b[k] * W2a[(32 + k) * 64 + t];
        bc[t] = bacc;
    }
}

// ---------------- xa = bf16(x @ W1a[0:32] + b1a), stored sigma-channel-permuted ----------------
__global__ __launch_bounds__(256) void k_xa(const float* __restrict__ x, const float* __restrict__ W1a,
                                            const float* __restrict__ b1a, uint32* __restrict__ xa, int N) {
    __shared__ float sW[32 * 64];
    __shared__ float sb[64];
    for (int t = threadIdx.x; t < 32 * 64; t += 256) sW[t] = W1a[t];
    if (threadIdx.x < 64) sb[threadIdx.x] = b1a[threadIdx.x];
    __syncthreads();
    int i = blockIdx.x * 256 + threadIdx.x;
    if (i >= N) return;
    float h[64];
    #pragma unroll
    for (int j = 0; j < 64; ++j) h[j] = sb[j];
    const float4* xrow = (const float4*)(x + (size_t)i * 32);
    #pragma unroll
    for (int k4 = 0; k4 < 8; ++k4) {
        float4 v = xrow[k4];
        float vv[4] = {v.x, v.y, v.z, v.w};
        #pragma unroll
        for (int c = 0; c < 4; ++c) {
            const float4* wr = (const float4*)&sW[(k4 * 4 + c) * 64];
            float val = vv[c];
            #pragma unroll
            for (int j4 = 0; j4 < 16; ++j4) {
                float4 w = wr[j4];
                h[j4 * 4 + 0] += val * w.x; h[j4 * 4 + 1] += val * w.y;
                h[j4 * 4 + 2] += val * w.z; h[j4 * 4 + 3] += val * w.w;
            }
        }
    }
    // permuted store: word[qq*8 + cc*2 + j] = pack(h[cc*16+qq*4+2j], h[cc*16+qq*4+2j+1])
    uint32* xap = xa + (size_t)i * 32;
    #pragma unroll
    for (int q = 0; q < 4; ++q) {
        uint4 t0, t1;
        t0.x = pack2(h[0 * 16 + q * 4 + 0], h[0 * 16 + q * 4 + 1]);
        t0.y = pack2(h[0 * 16 + q * 4 + 2], h[0 * 16 + q * 4 + 3]);
        t0.z = pack2(h[1 * 16 + q * 4 + 0], h[1 * 16 + q * 4 + 1]);
        t0.w = pack2(h[1 * 16 + q * 4 + 2], h[1 * 16 + q * 4 + 3]);
        t1.x = pack2(h[2 * 16 + q * 4 + 0], h[2 * 16 + q * 4 + 1]);
        t1.y = pack2(h[2 * 16 + q * 4 + 2], h[2 * 16 + q * 4 + 3]);
        t1.z = pack2(h[3 * 16 + q * 4 + 0], h[3 * 16 + q * 4 + 1]);
        t1.w = pack2(h[3 * 16 + q * 4 + 2], h[3 * 16 + q * 4 + 3]);
        *(uint4*)(xap + q * 8) = t0;
        *(uint4*)(xap + q * 8 + 4) = t1;
    }
}

// ---------------- MFMA edge kernel, operand-swapped: D[ch][edge], no LDS transpose, no in-loop barriers ----------------
// A = W1a_bot^T tile (channels on M), B = ea rows (edges on N), C preloaded with xa[col] (sigma-permuted).
// A frag: lane l -> row l&15, k=8*(l>>4)+i ; B frag: lane l -> col l&15, same k
// D/C: lane l -> col(edge)=l&15, row(ch-in-tile)=(l>>4)*4+r  => global ch = cc*16 + qq*4 + r = sigma-position qq*16+cc*4+r
__global__ __launch_bounds__(256) void k_edge_mfma(
    const int* __restrict__ ei, const float* __restrict__ ea, const uint32* __restrict__ xa,
    const float* __restrict__ W1a, const int* __restrict__ pos, uint32* __restrict__ g)
{
    __shared__ ushort16 sWt[64 * 32];  // [ch][k] bf16
    for (int idx = threadIdx.x; idx < 2048; idx += 256) {
        int ch = idx & 63, k = idx >> 6;
        sWt[ch * 32 + k] = (ushort16)bfbits(W1a[(32 + k) * 64 + ch]);
    }
    __syncthreads();

    int wave = threadIdx.x >> 6;
    int lane = threadIdx.x & 63;
    int en = lane & 15;   // edge-in-tile
    int qq = lane >> 4;   // k-group / channel sub-block

    bf16x8 bfr[4];
    #pragma unroll
    for (int cc = 0; cc < 4; ++cc)
        bfr[cc] = *(const bf16x8*)&sWt[(cc * 16 + en) * 32 + qq * 8];

    int base = blockIdx.x * (64 * TPW) + wave * (16 * TPW);

    #pragma unroll 1
    for (int t = 0; t < TPW; ++t) {
        int e = base + t * 16 + en;
        int col = ei[NE + e];
        int p = pos[e];

        // B frag: this edge's ea row, k-slice qq*8..+7, packed bf16
        const float* arow = ea + (size_t)e * 32 + qq * 8;
        float4 a0 = *(const float4*)arow;
        float4 a1 = *(const float4*)(arow + 4);
        union { uint4 u; bf16x8 v; } bf;
        bf.u.x = pack2(a0.x, a0.y);
        bf.u.y = pack2(a0.z, a0.w);
        bf.u.z = pack2(a1.x, a1.y);
        bf.u.w = pack2(a1.z, a1.w);

        // C init = xa[col] (sigma layout: lane qq reads words qq*8..qq*8+7)
        const uint4* xap = (const uint4*)(xa + (size_t)col * 32 + qq * 8);
        uint4 xv0 = xap[0];
        uint4 xv1 = xap[1];
        f32x4 acc[4];
        acc[0] = (f32x4){bflo(xv0.x), bfhi(xv0.x), bflo(xv0.y), bfhi(xv0.y)};
        acc[1] = (f32x4){bflo(xv0.z), bfhi(xv0.z), bflo(xv0.w), bfhi(xv0.w)};
        acc[2] = (f32x4){bflo(xv1.x), bfhi(xv1.x), bflo(xv1.y), bfhi(xv1.y)};
        acc[3] = (f32x4){bflo(xv1.z), bfhi(xv1.z), bflo(xv1.w), bfhi(xv1.w)};

        #pragma unroll
        for (int cc = 0; cc < 4; ++cc)
            acc[cc] = __builtin_amdgcn_mfma_f32_16x16x32_bf16(bfr[cc], bf.v, acc[cc], 0, 0, 0);

        // relu + pack + store: lane owns sigma-positions qq*16..qq*16+15 = words qq*8..+7 of row p
        uint4 o0, o1;
        o0.x = pack2(fmaxf(acc[0][0], 0.f), fmaxf(acc[0][1], 0.f));
        o0.y = pack2(fmaxf(acc[0][2], 0.f), fmaxf(acc[0][3], 0.f));
        o0.z = pack2(fmaxf(acc[1][0], 0.f), fmaxf(acc[1][1], 0.f));
        o0.w = pack2(fmaxf(acc[1][2], 0.f), fmaxf(acc[1][3], 0.f));
        o1.x = pack2(fmaxf(acc[2][0], 0.f), fmaxf(acc[2][1], 0.f));
        o1.y = pack2(fmaxf(acc[2][2], 0.f), fmaxf(acc[2][3], 0.f));
        o1.z = pack2(fmaxf(acc[3][0], 0.f), fmaxf(acc[3][1], 0.f));
        o1.w = pack2(fmaxf(acc[3][2], 0.f), fmaxf(acc[3][3], 0.f));
        uint4* gp = (uint4*)(g + (size_t)p * 32 + qq * 8);
        gp[0] = o0;
        gp[1] = o1;
    }
}

// ---------------- segment sum over CONTIGUOUS g rows (channel-order agnostic) ----------------
__global__ __launch_bounds__(256) void k_seg_c(
    const int* __restrict__ deg, const int* __restrict__ offs,
    const uint32* __restrict__ g, float* __restrict__ Sacc)
{
    int node = blockIdx.x * 4 + (threadIdx.x >> 6);
    if (node >= NN) return;
    int lane = threadIdx.x & 63;
    int half = lane >> 5;   // row parity
    int ui = lane & 31;     // word index (2 sigma-channels)
    int d = deg[node];
    size_t start = (size_t)offs[node];
    float S0 = 0.f, S1 = 0.f;
    for (int r = half; r < d; r += 2) {
        uint32 u = g[(start + r) * 32 + ui];
        S0 += bflo(u);
        S1 += bfhi(u);
    }
    S0 += __shfl_xor(S0, 32);
    S1 += __shfl_xor(S1, 32);
    if (half == 0) {
        float2* sp = (float2*)(Sacc + (size_t)node * 64);
        sp[ui] = make_float2(S0, S1);
    }
}

// ---------------- fallback: per-edge atomic scatter (original channel order) ----------------
__global__ __launch_bounds__(256) void k_edge_atom(
    const float* __restrict__ x, const int* __restrict__ ei, const float* __restrict__ ea,
    const float* __restrict__ W1a, const float* __restrict__ b1a,
    float* __restrict__ Sacc, int E)
{
    __shared__ float sWB[32 * 64];
    __shared__ float sWA[32 * 64];
    __shared__ float sb[64];
    for (int t = threadIdx.x; t < 32 * 64; t += 256) {
        sWB[t] = W1a[32 * 64 + t];
        sWA[t] = W1a[t];
    }
    if (threadIdx.x < 64) sb[threadIdx.x] = b1a[threadIdx.x];
    __syncthreads();
    int e = blockIdx.x * 256 + threadIdx.x;
    if (e >= E) return;
    int row = ei[e];
    int col = ei[NE + e];
    float h[64];
    #pragma unroll
    for (int j = 0; j < 64; ++j) h[j] = sb[j];
    const float4* xrow = (const float4*)(x + (size_t)col * 32);
    #pragma unroll
    for (int k4 = 0; k4 < 8; ++k4) {
        float4 v = xrow[k4];
        float vv[4] = {v.x, v.y, v.z, v.w};
        #pragma unroll
        for (int c = 0; c < 4; ++c) {
            float val = vv[c];
            const float4* wr = (const float4*)&sWA[(k4 * 4 + c) * 64];
            #pragma unroll
            for (int j4 = 0; j4 < 16; ++j4) {
                float4 w = wr[j4];
                h[j4 * 4 + 0] += val * w.x; h[j4 * 4 + 1] += val * w.y;
                h[j4 * 4 + 2] += val * w.z; h[j4 * 4 + 3] += val * w.w;
            }
        }
    }
    const float4* earow = (const float4*)(ea + (size_t)e * 32);
    #pragma unroll
    for (int k4 = 0; k4 < 8; ++k4) {
        float4 v = earow[k4];
        float vv[4] = {v.x, v.y, v.z, v.w};
        #pragma unroll
        for (int c = 0; c < 4; ++c) {
            float val = vv[c];
            const float4* wr = (const float4*)&sWB[(k4 * 4 + c) * 64];
            #pragma unroll
            for (int j4 = 0; j4 < 16; ++j4) {
                float4 w = wr[j4];
                h[j4 * 4 + 0] += val * w.x; h[j4 * 4 + 1] += val * w.y;
                h[j4 * 4 + 2] += val * w.z; h[j4 * 4 + 3] += val * w.w;
            }
        }
    }
    float* srow = Sacc + (size_t)row * 64;
    #pragma unroll
    for (int j = 0; j < 64; ++j) atomicAdd(&srow[j], fmaxf(h[j], 0.f));
}

// ---------------- node MLP: out = relu(x@W2a_top + (Sacc/d)@Wc + bc + b2a) @ W2b + b2b ----------------
__global__ __launch_bounds__(256) void k_node(
    const float* __restrict__ x, const float* __restrict__ Sacc, const int* __restrict__ deg,
    const float* __restrict__ Wc, const float* __restrict__ bc,
    const float* __restrict__ W2a, const float* __restrict__ b2a,
    const float* __restrict__ W2b, const float* __restrict__ b2b,
    float* __restrict__ out, int N)
{
    __shared__ float sWc[64 * 64];
    __shared__ float sW2ax[32 * 64];
    __shared__ float sW2b[64 * 32];
    __shared__ float sbc2[64];
    __shared__ float sb2[64];
    __shared__ float sb2b_[32];
    for (int t = threadIdx.x; t < 64 * 64; t += 256) sWc[t] = Wc[t];
    for (int t = threadIdx.x; t < 32 * 64; t += 256) sW2ax[t] = W2a[t];
    for (int t = threadIdx.x; t < 64 * 32; t += 256) sW2b[t] = W2b[t];
    if (threadIdx.x < 64) {
        sbc2[threadIdx.x] = bc[threadIdx.x] + b2a[threadIdx.x];
        sb2[threadIdx.x] = b2a[threadIdx.x];
    }
    if (threadIdx.x < 32) sb2b_[threadIdx.x] = b2b[threadIdx.x];
    __syncthreads();

    int i = blockIdx.x * 256 + threadIdx.x;
    if (i >= N) return;
    int d = deg[i];
    float inv = (d > 0) ? 1.f / (float)d : 0.f;

    float h2[64];
    #pragma unroll
    for (int j = 0; j < 64; ++j) h2[j] = (d > 0) ? sbc2[j] : sb2[j];

    const float4* sp = (const float4*)(Sacc + (size_t)i * 64);
    #pragma unroll 2
    for (int k4 = 0; k4 < 16; ++k4) {
        float4 v = sp[k4];
        float vv[4] = {v.x * inv, v.y * inv, v.z * inv, v.w * inv};
        #pragma unroll
        for (int c = 0; c < 4; ++c) {
            float val = vv[c];
            const float4* wr = (const float4*)&sWc[(k4 * 4 + c) * 64];
            #pragma unroll
            for (int j4 = 0; j4 < 16; ++j4) {
                float4 w = wr[j4];
                h2[j4 * 4 + 0] += val * w.x; h2[j4 * 4 + 1] += val * w.y;
                h2[j4 * 4 + 2] += val * w.z; h2[j4 * 4 + 3] += val * w.w;
            }
        }
    }
    const float4* xrow = (const float4*)(x + (size_t)i * 32);
    #pragma unroll 2
    for (int k4 = 0; k4 < 8; ++k4) {
        float4 v = xrow[k4];
        float vv[4] = {v.x, v.y, v.z, v.w};
        #pragma unroll
        for (int c = 0; c < 4; ++c) {
            float val = vv[c];
            const float4* wr = (const float4*)&sW2ax[(k4 * 4 + c) * 64];
            #pragma unroll
            for (int j4 = 0; j4 < 16; ++j4) {
                float4 w = wr[j4];
                h2[j4 * 4 + 0] += val * w.x; h2[j4 * 4 + 1] += val * w.y;
                h2[j4 * 4 + 2] += val * w.z; h2[j4 * 4 + 3] += val * w.w;
            }
        }
    }
    #pragma unroll
    for (int j = 0; j < 64; ++j) h2[j] = fmaxf(h2[j], 0.f);

    float o[32];
    #pragma unroll
    for (int j = 0; j < 32; ++j) o[j] = sb2b_[j];
    #pragma unroll
    for (int k = 0; k < 64; ++k) {
        float val = h2[k];
        const float4* wr = (const float4*)&sW2b[k * 32];
        #pragma unroll
        for (int j4 = 0; j4 < 8; ++j4) {
            float4 w = wr[j4];
            o[j4 * 4 + 0] += val * w.x; o[j4 * 4 + 1] += val * w.y;
            o[j4 * 4 + 2] += val * w.z; o[j4 * 4 + 3] += val * w.w;
        }
    }
    float4* orow = (float4*)(out + (size_t)i * 32);
    #pragma unroll
    for (int q = 0; q < 8; ++q)
        orow[q] = make_float4(o[q * 4], o[q * 4 + 1], o[q * 4 + 2], o[q * 4 + 3]);
}

extern "C" void kernel_launch(void* const* d_in, const int* in_sizes, int n_in,
                              void* d_out, int out_size, void* d_ws, size_t ws_size,
                              hipStream_t stream) {
    const float* x   = (const float*)d_in[0];
    const int*   ei  = (const int*)d_in[1];
    const float* ea  = (const float*)d_in[2];
    const float* W1a = (const float*)d_in[5];
    const float* b1a = (const float*)d_in[6];
    const float* W1b = (const float*)d_in[7];
    const float* b1b = (const float*)d_in[8];
    const float* W2a = (const float*)d_in[9];
    const float* b2a = (const float*)d_in[10];
    const float* W2b = (const float*)d_in[11];
    const float* b2b = (const float*)d_in[12];
    float* out = (float*)d_out;

    // workspace layout
    char* p = (char*)d_ws;
    int* deg        = (int*)p;        p += (size_t)NN * 4;
    int* cursor     = (int*)p;        p += (size_t)NN * 4;   // adjacent to deg: single memset
    int* offs       = (int*)p;        p += (size_t)NN * 4;
    int* bsums      = (int*)p;        p += 2048;
    float* Wc       = (float*)p;      p += 4096 * 4;
    float* bc       = (float*)p;      p += 64 * 4;
    int* pos        = (int*)p;        p += (size_t)NE * 4;
    uint32* xa      = (uint32*)p;     p += (size_t)NN * 64 * 2;
    float* Sacc     = (float*)p;      p += (size_t)NN * 64 * 4;
    size_t off_g    = (size_t)(p - (char*)d_ws);             // ~46 MB
    uint32* g       = (uint32*)p;

    dim3 blk(256);
    bool primary = (ws_size >= off_g + (size_t)NE * 128);    // full g fits (R4/R5 evidence: yes)

    if (primary) {
        hipMemsetAsync(deg, 0, (size_t)2 * NN * 4, stream);  // deg + cursor
        hipLaunchKernelGGL(k_hist, dim3((NE + 255) / 256), blk, 0, stream, ei, deg, NE);
        hipLaunchKernelGGL(k_scan1, dim3(NB), blk, 0, stream, deg, offs, bsums, NN);
        hipLaunchKernelGGL(k_scan2, dim3(1), dim3(512), 0, stream, bsums, NB);
        hipLaunchKernelGGL(k_scan3, dim3(NB), blk, 0, stream, offs, bsums, NN);
        hipLaunchKernelGGL(k_scatter_pos, dim3((NE + 255) / 256), blk, 0, stream, ei, offs, cursor, pos, NE);
        hipLaunchKernelGGL(k_prep, dim3(16), blk, 0, stream, W1b, b1b, W2a, Wc, bc, 1);
        hipLaunchKernelGGL(k_xa, dim3(NB), blk, 0, stream, x, W1a, b1a, xa, NN);
        hipLaunchKernelGGL(k_edge_mfma, dim3(NE / (64 * TPW)), blk, 0, stream, ei, ea, xa, W1a, pos, g);
        hipLaunchKernelGGL(k_seg_c, dim3((NN + 3) / 4), blk, 0, stream, deg, offs, g, Sacc);
        hipLaunchKernelGGL(k_node, dim3(NB), blk, 0, stream,
                           x, Sacc, deg, Wc, bc, W2a, b2a, W2b, b2b, out, NN);
    } else {
        // fallback: fp32 atomic scatter (original channel order)
        hipMemsetAsync(deg, 0, (size_t)NN * 4, stream);
        hipMemsetAsync(Sacc, 0, (size_t)NN * 64 * 4, stream);
        hipLaunchKernelGGL(k_hist, dim3((NE + 255) / 256), blk, 0, stream, ei, deg, NE);
        hipLaunchKernelGGL(k_prep, dim3(16), blk, 0, stream, W1b, b1b, W2a, Wc, bc, 0);
        hipLaunchKernelGGL(k_edge_atom, dim3((NE + 255) / 256), blk, 0, stream,
                           x, ei, ea, W1a, b1a, Sacc, NE);
        hipLaunchKernelGGL(k_node, dim3(NB), blk, 0, stream,
                           x, Sacc, deg, Wc, bc, W2a, b2a, W2b, b2b, out, NN);
    }
}

// Round 7
// 331.933 us; speedup vs baseline: 34.9185x; 1.2677x over previous
//
#include <hip/hip_runtime.h>

#define NN 100000
#define NE 1600000
#define NB ((NN + 255) / 256)
#define TPW 8   // 16-edge tiles per wave in k_edge_mfma

typedef unsigned int uint32;
typedef unsigned short ushort16;
typedef float f32x4 __attribute__((ext_vector_type(4)));
typedef short bf16x8 __attribute__((ext_vector_type(8)));

__device__ __forceinline__ float bflo(uint32 u) { return __uint_as_float(u << 16); }
__device__ __forceinline__ float bfhi(uint32 u) { return __uint_as_float(u & 0xffff0000u); }
__device__ __forceinline__ uint32 bfbits(float v) { return (__float_as_uint(v) + 0x8000u) >> 16; }
__device__ __forceinline__ uint32 pack2(float a, float b) { return bfbits(a) | (bfbits(b) << 16); }

// channel permutation: sigma(c) swaps cc (bits 5:4) and qq (bits 3:2) fields
__device__ __forceinline__ int sigma_ch(int c) {
    return (((c >> 2) & 3) << 4) + (((c >> 4) & 3) << 2) + (c & 3);
}

// ---------------- CSR build ----------------
// single atomic pass: deg counts + per-edge rank (stored into pos[])
__global__ __launch_bounds__(256) void k_hist_rank(const int* __restrict__ ei, int* __restrict__ deg,
                                                   int* __restrict__ pos, int E) {
    int e = blockIdx.x * 256 + threadIdx.x;
    if (e < E) pos[e] = atomicAdd(&deg[ei[e]], 1);
}

__global__ __launch_bounds__(256) void k_hist(const int* __restrict__ ei, int* __restrict__ deg, int E) {
    int e = blockIdx.x * 256 + threadIdx.x;
    if (e < E) atomicAdd(&deg[ei[e]], 1);
}

__global__ __launch_bounds__(256) void k_scan1(const int* __restrict__ deg, int* __restrict__ offs,
                                               int* __restrict__ bsums, int n) {
    __shared__ int s[256];
    int tid = threadIdx.x;
    int i = blockIdx.x * 256 + tid;
    int v = (i < n) ? deg[i] : 0;
    int acc = v;
    s[tid] = acc;
    __syncthreads();
    #pragma unroll
    for (int off = 1; off < 256; off <<= 1) {
        int t = (tid >= off) ? s[tid - off] : 0;
        __syncthreads();
        acc += t;
        s[tid] = acc;
        __syncthreads();
    }
    if (i < n) offs[i] = acc - v;
    if (tid == 255) bsums[blockIdx.x] = acc;
}

__global__ __launch_bounds__(512) void k_scan2(int* __restrict__ bsums, int nb) {
    __shared__ int s[512];
    int tid = threadIdx.x;
    int v = (tid < nb) ? bsums[tid] : 0;
    int acc = v;
    s[tid] = acc;
    __syncthreads();
    #pragma unroll
    for (int off = 1; off < 512; off <<= 1) {
        int t = (tid >= off) ? s[tid - off] : 0;
        __syncthreads();
        acc += t;
        s[tid] = acc;
        __syncthreads();
    }
    bsums[tid] = acc - v;
}

// finalize pos in place: pos[e] = rank + exclusive-prefix(row)
__global__ __launch_bounds__(256) void k_pos(const int* __restrict__ ei, const int* __restrict__ offs,
                                             const int* __restrict__ bsums, int* __restrict__ pos, int E) {
    int e = blockIdx.x * 256 + threadIdx.x;
    if (e >= E) return;
    int r = ei[e];
    pos[e] += offs[r] + bsums[r >> 8];
}

// ---------------- Wc = W1b @ W2a[32:96] (rows sigma-permuted when perm=1), bc = b1b @ W2a[32:96] ----------------
__global__ __launch_bounds__(256) void k_prep(const float* __restrict__ W1b, const float* __restrict__ b1b,
                                              const float* __restrict__ W2a,
                                              float* __restrict__ Wc, float* __restrict__ bc, int perm) {
    int t = blockIdx.x * 256 + threadIdx.x;  // 0..4095
    int r = t >> 6, c = t & 63;
    float a = 0.f;
    for (int k = 0; k < 64; ++k) a += W1b[r * 64 + k] * W2a[(32 + k) * 64 + c];
    int rs = perm ? sigma_ch(r) : r;
    Wc[rs * 64 + c] = a;
    if (t < 64) {
        float bacc = 0.f;
        for (int k = 0; k < 64; ++k) bacc += b1b[k] * W2a[(32 + k) * 64 + t];
        bc[t] = bacc;
    }
}

// ---------------- xa = bf16(x @ W1a[0:32] + b1a), stored sigma-channel-permuted ----------------
__global__ __launch_bounds__(256) void k_xa(const float* __restrict__ x, const float* __restrict__ W1a,
                                            const float* __restrict__ b1a, uint32* __restrict__ xa, int N) {
    __shared__ float sW[32 * 64];
    __shared__ float sb[64];
    for (int t = threadIdx.x; t < 32 * 64; t += 256) sW[t] = W1a[t];
    if (threadIdx.x < 64) sb[threadIdx.x] = b1a[threadIdx.x];
    __syncthreads();
    int i = blockIdx.x * 256 + threadIdx.x;
    if (i >= N) return;
    float h[64];
    #pragma unroll
    for (int j = 0; j < 64; ++j) h[j] = sb[j];
    const float4* xrow = (const float4*)(x + (size_t)i * 32);
    #pragma unroll
    for (int k4 = 0; k4 < 8; ++k4) {
        float4 v = xrow[k4];
        float vv[4] = {v.x, v.y, v.z, v.w};
        #pragma unroll
        for (int c = 0; c < 4; ++c) {
            const float4* wr = (const float4*)&sW[(k4 * 4 + c) * 64];
            float val = vv[c];
            #pragma unroll
            for (int j4 = 0; j4 < 16; ++j4) {
                float4 w = wr[j4];
                h[j4 * 4 + 0] += val * w.x; h[j4 * 4 + 1] += val * w.y;
                h[j4 * 4 + 2] += val * w.z; h[j4 * 4 + 3] += val * w.w;
            }
        }
    }
    uint32* xap = xa + (size_t)i * 32;
    #pragma unroll
    for (int q = 0; q < 4; ++q) {
        uint4 t0, t1;
        t0.x = pack2(h[0 * 16 + q * 4 + 0], h[0 * 16 + q * 4 + 1]);
        t0.y = pack2(h[0 * 16 + q * 4 + 2], h[0 * 16 + q * 4 + 3]);
        t0.z = pack2(h[1 * 16 + q * 4 + 0], h[1 * 16 + q * 4 + 1]);
        t0.w = pack2(h[1 * 16 + q * 4 + 2], h[1 * 16 + q * 4 + 3]);
        t1.x = pack2(h[2 * 16 + q * 4 + 0], h[2 * 16 + q * 4 + 1]);
        t1.y = pack2(h[2 * 16 + q * 4 + 2], h[2 * 16 + q * 4 + 3]);
        t1.z = pack2(h[3 * 16 + q * 4 + 0], h[3 * 16 + q * 4 + 1]);
        t1.w = pack2(h[3 * 16 + q * 4 + 2], h[3 * 16 + q * 4 + 3]);
        *(uint4*)(xap + q * 8) = t0;
        *(uint4*)(xap + q * 8 + 4) = t1;
    }
}

// ---------------- MFMA edge kernel, depth-2 software pipeline ----------------
// A = W1a_bot^T (channels on M), B = ea row (edge on col), C preloaded with xa[col] (sigma layout).
// D/C: lane l -> col(edge)=l&15, rows = channels; lane owns edge en, channels qq*16..+15 (sigma order).
__global__ __launch_bounds__(256) void k_edge_mfma(
    const int* __restrict__ ei, const float* __restrict__ ea, const uint32* __restrict__ xa,
    const float* __restrict__ W1a, const int* __restrict__ pos, uint32* __restrict__ g)
{
    __shared__ ushort16 sWt[64 * 40];  // [ch][k] bf16, row padded to 40 (80B: 16B-aligned, conflict-free)
    for (int idx = threadIdx.x; idx < 2048; idx += 256) {
        int ch = idx & 63, k = idx >> 6;
        sWt[ch * 40 + k] = (ushort16)bfbits(W1a[(32 + k) * 64 + ch]);  // coalesced read
    }
    __syncthreads();

    int lane = threadIdx.x & 63;
    int wave = threadIdx.x >> 6;
    int en = lane & 15;   // edge-in-tile
    int qq = lane >> 4;   // k-group / channel sub-block

    bf16x8 bfr[4];
    #pragma unroll
    for (int cc = 0; cc < 4; ++cc)
        bfr[cc] = *(const bf16x8*)&sWt[(cc * 16 + en) * 40 + qq * 8];

    int base = blockIdx.x * (64 * TPW) + wave * (16 * TPW);

    // ---- prologue: tile 0 fully issued, tile 1 L1-issued ----
    int e0 = base + en;
    int c0 = ei[NE + e0];
    int p0 = pos[e0];
    float4 f0a = *(const float4*)(ea + (size_t)e0 * 32 + qq * 8);
    float4 f0b = *(const float4*)(ea + (size_t)e0 * 32 + qq * 8 + 4);

    int e1 = base + 16 + en;
    int c1 = ei[NE + e1];
    int p1 = pos[e1];
    float4 f1a = *(const float4*)(ea + (size_t)e1 * 32 + qq * 8);
    float4 f1b = *(const float4*)(ea + (size_t)e1 * 32 + qq * 8 + 4);

    uint4 xv0a = *(const uint4*)(xa + (size_t)c0 * 32 + qq * 8);
    uint4 xv0b = *(const uint4*)(xa + (size_t)c0 * 32 + qq * 8 + 4);

    #pragma unroll 1
    for (int t = 0; t < TPW; ++t) {
        // issue L1 for tile t+2 (clamped; compute never uses clamped values)
        int e2 = base + (t + 2) * 16 + en;
        if (e2 > NE - 1) e2 = NE - 1;
        int c2 = ei[NE + e2];
        int p2 = pos[e2];
        float4 f2a = *(const float4*)(ea + (size_t)e2 * 32 + qq * 8);
        float4 f2b = *(const float4*)(ea + (size_t)e2 * 32 + qq * 8 + 4);
        // issue xa gather for tile t+1 (c1 was issued one iteration ago)
        uint4 xv1a = *(const uint4*)(xa + (size_t)c1 * 32 + qq * 8);
        uint4 xv1b = *(const uint4*)(xa + (size_t)c1 * 32 + qq * 8 + 4);

        // ---- compute tile t ----
        union { uint4 u; bf16x8 v; } bf;
        bf.u.x = pack2(f0a.x, f0a.y);
        bf.u.y = pack2(f0a.z, f0a.w);
        bf.u.z = pack2(f0b.x, f0b.y);
        bf.u.w = pack2(f0b.z, f0b.w);

        f32x4 acc[4];
        acc[0] = (f32x4){bflo(xv0a.x), bfhi(xv0a.x), bflo(xv0a.y), bfhi(xv0a.y)};
        acc[1] = (f32x4){bflo(xv0a.z), bfhi(xv0a.z), bflo(xv0a.w), bfhi(xv0a.w)};
        acc[2] = (f32x4){bflo(xv0b.x), bfhi(xv0b.x), bflo(xv0b.y), bfhi(xv0b.y)};
        acc[3] = (f32x4){bflo(xv0b.z), bfhi(xv0b.z), bflo(xv0b.w), bfhi(xv0b.w)};

        #pragma unroll
        for (int cc = 0; cc < 4; ++cc)
            acc[cc] = __builtin_amdgcn_mfma_f32_16x16x32_bf16(bfr[cc], bf.v, acc[cc], 0, 0, 0);

        uint4 o0, o1;
        o0.x = pack2(fmaxf(acc[0][0], 0.f), fmaxf(acc[0][1], 0.f));
        o0.y = pack2(fmaxf(acc[0][2], 0.f), fmaxf(acc[0][3], 0.f));
        o0.z = pack2(fmaxf(acc[1][0], 0.f), fmaxf(acc[1][1], 0.f));
        o0.w = pack2(fmaxf(acc[1][2], 0.f), fmaxf(acc[1][3], 0.f));
        o1.x = pack2(fmaxf(acc[2][0], 0.f), fmaxf(acc[2][1], 0.f));
        o1.y = pack2(fmaxf(acc[2][2], 0.f), fmaxf(acc[2][3], 0.f));
        o1.z = pack2(fmaxf(acc[3][0], 0.f), fmaxf(acc[3][1], 0.f));
        o1.w = pack2(fmaxf(acc[3][2], 0.f), fmaxf(acc[3][3], 0.f));
        uint4* gp = (uint4*)(g + (size_t)p0 * 32 + qq * 8);
        gp[0] = o0;
        gp[1] = o1;

        // ---- rotate pipeline registers (all names static) ----
        c0 = c1; p0 = p1; f0a = f1a; f0b = f1b;
        xv0a = xv1a; xv0b = xv1b;
        c1 = c2; p1 = p2; f1a = f2a; f1b = f2b;
    }
}

// ---------------- segment sum over contiguous g rows: wave/node, 4 rows/iter ----------------
__global__ __launch_bounds__(256) void k_seg_c(
    const int* __restrict__ deg, const int* __restrict__ offs, const int* __restrict__ bsums,
    const uint32* __restrict__ g, float* __restrict__ Sacc)
{
    int node = blockIdx.x * 4 + (threadIdx.x >> 6);
    if (node >= NN) return;
    int lane = threadIdx.x & 63;
    int quarter = lane >> 4;   // row slot within group of 4
    int wi = lane & 15;        // uint2 index within 128B row
    int d = deg[node];
    size_t start = (size_t)(offs[node] + bsums[node >> 8]);

    float4 S = {0.f, 0.f, 0.f, 0.f};
    int r = quarter;
    for (; r + 4 < d; r += 8) {
        uint2 u1 = *(const uint2*)(g + (start + r) * 32 + wi * 2);
        uint2 u2 = *(const uint2*)(g + (start + r + 4) * 32 + wi * 2);
        S.x += bflo(u1.x) + bflo(u2.x);
        S.y += bfhi(u1.x) + bfhi(u2.x);
        S.z += bflo(u1.y) + bflo(u2.y);
        S.w += bfhi(u1.y) + bfhi(u2.y);
    }
    if (r < d) {
        uint2 u = *(const uint2*)(g + (start + r) * 32 + wi * 2);
        S.x += bflo(u.x); S.y += bfhi(u.x); S.z += bflo(u.y); S.w += bfhi(u.y);
    }
    // reduce across quarters (lane bits 4,5)
    S.x += __shfl_xor(S.x, 16); S.y += __shfl_xor(S.y, 16);
    S.z += __shfl_xor(S.z, 16); S.w += __shfl_xor(S.w, 16);
    S.x += __shfl_xor(S.x, 32); S.y += __shfl_xor(S.y, 32);
    S.z += __shfl_xor(S.z, 32); S.w += __shfl_xor(S.w, 32);
    if (quarter == 0)
        *(float4*)(Sacc + (size_t)node * 64 + wi * 4) = make_float4(S.x, S.y, S.z, S.w);
}

// ---------------- fallback: per-edge atomic scatter (original channel order) ----------------
__global__ __launch_bounds__(256) void k_edge_atom(
    const float* __restrict__ x, const int* __restrict__ ei, const float* __restrict__ ea,
    const float* __restrict__ W1a, const float* __restrict__ b1a,
    float* __restrict__ Sacc, int E)
{
    __shared__ float sWB[32 * 64];
    __shared__ float sWA[32 * 64];
    __shared__ float sb[64];
    for (int t = threadIdx.x; t < 32 * 64; t += 256) {
        sWB[t] = W1a[32 * 64 + t];
        sWA[t] = W1a[t];
    }
    if (threadIdx.x < 64) sb[threadIdx.x] = b1a[threadIdx.x];
    __syncthreads();
    int e = blockIdx.x * 256 + threadIdx.x;
    if (e >= E) return;
    int row = ei[e];
    int col = ei[NE + e];
    float h[64];
    #pragma unroll
    for (int j = 0; j < 64; ++j) h[j] = sb[j];
    const float4* xrow = (const float4*)(x + (size_t)col * 32);
    #pragma unroll
    for (int k4 = 0; k4 < 8; ++k4) {
        float4 v = xrow[k4];
        float vv[4] = {v.x, v.y, v.z, v.w};
        #pragma unroll
        for (int c = 0; c < 4; ++c) {
            float val = vv[c];
            const float4* wr = (const float4*)&sWA[(k4 * 4 + c) * 64];
            #pragma unroll
            for (int j4 = 0; j4 < 16; ++j4) {
                float4 w = wr[j4];
                h[j4 * 4 + 0] += val * w.x; h[j4 * 4 + 1] += val * w.y;
                h[j4 * 4 + 2] += val * w.z; h[j4 * 4 + 3] += val * w.w;
            }
        }
    }
    const float4* earow = (const float4*)(ea + (size_t)e * 32);
    #pragma unroll
    for (int k4 = 0; k4 < 8; ++k4) {
        float4 v = earow[k4];
        float vv[4] = {v.x, v.y, v.z, v.w};
        #pragma unroll
        for (int c = 0; c < 4; ++c) {
            float val = vv[c];
            const float4* wr = (const float4*)&sWB[(k4 * 4 + c) * 64];
            #pragma unroll
            for (int j4 = 0; j4 < 16; ++j4) {
                float4 w = wr[j4];
                h[j4 * 4 + 0] += val * w.x; h[j4 * 4 + 1] += val * w.y;
                h[j4 * 4 + 2] += val * w.z; h[j4 * 4 + 3] += val * w.w;
            }
        }
    }
    float* srow = Sacc + (size_t)row * 64;
    #pragma unroll
    for (int j = 0; j < 64; ++j) atomicAdd(&srow[j], fmaxf(h[j], 0.f));
}

// ---------------- node MLP: out = relu(x@W2a_top + (Sacc/d)@Wc + bc + b2a) @ W2b + b2b ----------------
__global__ __launch_bounds__(256) void k_node(
    const float* __restrict__ x, const float* __restrict__ Sacc, const int* __restrict__ deg,
    const float* __restrict__ Wc, const float* __restrict__ bc,
    const float* __restrict__ W2a, const float* __restrict__ b2a,
    const float* __restrict__ W2b, const float* __restrict__ b2b,
    float* __restrict__ out, int N)
{
    __shared__ float sWc[64 * 64];
    __shared__ float sW2ax[32 * 64];
    __shared__ float sW2b[64 * 32];
    __shared__ float sbc2[64];
    __shared__ float sb2[64];
    __shared__ float sb2b_[32];
    for (int t = threadIdx.x; t < 64 * 64; t += 256) sWc[t] = Wc[t];
    for (int t = threadIdx.x; t < 32 * 64; t += 256) sW2ax[t] = W2a[t];
    for (int t = threadIdx.x; t < 64 * 32; t += 256) sW2b[t] = W2b[t];
    if (threadIdx.x < 64) {
        sbc2[threadIdx.x] = bc[threadIdx.x] + b2a[threadIdx.x];
        sb2[threadIdx.x] = b2a[threadIdx.x];
    }
    if (threadIdx.x < 32) sb2b_[threadIdx.x] = b2b[threadIdx.x];
    __syncthreads();

    int i = blockIdx.x * 256 + threadIdx.x;
    if (i >= N) return;
    int d = deg[i];
    float inv = (d > 0) ? 1.f / (float)d : 0.f;

    float h2[64];
    #pragma unroll
    for (int j = 0; j < 64; ++j) h2[j] = (d > 0) ? sbc2[j] : sb2[j];

    const float4* sp = (const float4*)(Sacc + (size_t)i * 64);
    #pragma unroll 2
    for (int k4 = 0; k4 < 16; ++k4) {
        float4 v = sp[k4];
        float vv[4] = {v.x * inv, v.y * inv, v.z * inv, v.w * inv};
        #pragma unroll
        for (int c = 0; c < 4; ++c) {
            float val = vv[c];
            const float4* wr = (const float4*)&sWc[(k4 * 4 + c) * 64];
            #pragma unroll
            for (int j4 = 0; j4 < 16; ++j4) {
                float4 w = wr[j4];
                h2[j4 * 4 + 0] += val * w.x; h2[j4 * 4 + 1] += val * w.y;
                h2[j4 * 4 + 2] += val * w.z; h2[j4 * 4 + 3] += val * w.w;
            }
        }
    }
    const float4* xrow = (const float4*)(x + (size_t)i * 32);
    #pragma unroll 2
    for (int k4 = 0; k4 < 8; ++k4) {
        float4 v = xrow[k4];
        float vv[4] = {v.x, v.y, v.z, v.w};
        #pragma unroll
        for (int c = 0; c < 4; ++c) {
            float val = vv[c];
            const float4* wr = (const float4*)&sW2ax[(k4 * 4 + c) * 64];
            #pragma unroll
            for (int j4 = 0; j4 < 16; ++j4) {
                float4 w = wr[j4];
                h2[j4 * 4 + 0] += val * w.x; h2[j4 * 4 + 1] += val * w.y;
                h2[j4 * 4 + 2] += val * w.z; h2[j4 * 4 + 3] += val * w.w;
            }
        }
    }
    #pragma unroll
    for (int j = 0; j < 64; ++j) h2[j] = fmaxf(h2[j], 0.f);

    float o[32];
    #pragma unroll
    for (int j = 0; j < 32; ++j) o[j] = sb2b_[j];
    #pragma unroll
    for (int k = 0; k < 64; ++k) {
        float val = h2[k];
        const float4* wr = (const float4*)&sW2b[k * 32];
        #pragma unroll
        for (int j4 = 0; j4 < 8; ++j4) {
            float4 w = wr[j4];
            o[j4 * 4 + 0] += val * w.x; o[j4 * 4 + 1] += val * w.y;
            o[j4 * 4 + 2] += val * w.z; o[j4 * 4 + 3] += val * w.w;
        }
    }
    float4* orow = (float4*)(out + (size_t)i * 32);
    #pragma unroll
    for (int q = 0; q < 8; ++q)
        orow[q] = make_float4(o[q * 4], o[q * 4 + 1], o[q * 4 + 2], o[q * 4 + 3]);
}

extern "C" void kernel_launch(void* const* d_in, const int* in_sizes, int n_in,
                              void* d_out, int out_size, void* d_ws, size_t ws_size,
                              hipStream_t stream) {
    const float* x   = (const float*)d_in[0];
    const int*   ei  = (const int*)d_in[1];
    const float* ea  = (const float*)d_in[2];
    const float* W1a = (const float*)d_in[5];
    const float* b1a = (const float*)d_in[6];
    const float* W1b = (const float*)d_in[7];
    const float* b1b = (const float*)d_in[8];
    const float* W2a = (const float*)d_in[9];
    const float* b2a = (const float*)d_in[10];
    const float* W2b = (const float*)d_in[11];
    const float* b2b = (const float*)d_in[12];
    float* out = (float*)d_out;

    // workspace layout (~250.5 MB total; rank aliased into pos)
    char* p = (char*)d_ws;
    int* deg        = (int*)p;        p += (size_t)NN * 4;
    int* offs       = (int*)p;        p += (size_t)NN * 4;
    int* bsums      = (int*)p;        p += 2048;
    float* Wc       = (float*)p;      p += 4096 * 4;
    float* bc       = (float*)p;      p += 64 * 4;
    int* pos        = (int*)p;        p += (size_t)NE * 4;        // rank, then final slot
    uint32* xa      = (uint32*)p;     p += (size_t)NN * 64 * 2;
    float* Sacc     = (float*)p;      p += (size_t)NN * 64 * 4;
    size_t off_g    = (size_t)(p - (char*)d_ws);
    uint32* g       = (uint32*)p;

    dim3 blk(256);
    bool primary = (ws_size >= off_g + (size_t)NE * 128);

    if (primary) {
        hipMemsetAsync(deg, 0, (size_t)NN * 4, stream);
        hipLaunchKernelGGL(k_hist_rank, dim3((NE + 255) / 256), blk, 0, stream, ei, deg, pos, NE);
        hipLaunchKernelGGL(k_scan1, dim3(NB), blk, 0, stream, deg, offs, bsums, NN);
        hipLaunchKernelGGL(k_scan2, dim3(1), dim3(512), 0, stream, bsums, NB);
        hipLaunchKernelGGL(k_pos, dim3((NE + 255) / 256), blk, 0, stream, ei, offs, bsums, pos, NE);
        hipLaunchKernelGGL(k_prep, dim3(16), blk, 0, stream, W1b, b1b, W2a, Wc, bc, 1);
        hipLaunchKernelGGL(k_xa, dim3(NB), blk, 0, stream, x, W1a, b1a, xa, NN);
        hipLaunchKernelGGL(k_edge_mfma, dim3(NE / (64 * TPW)), blk, 0, stream, ei, ea, xa, W1a, pos, g);
        hipLaunchKernelGGL(k_seg_c, dim3((NN + 3) / 4), blk, 0, stream, deg, offs, bsums, g, Sacc);
        hipLaunchKernelGGL(k_node, dim3(NB), blk, 0, stream,
                           x, Sacc, deg, Wc, bc, W2a, b2a, W2b, b2b, out, NN);
    } else {
        // fallback: fp32 atomic scatter (original channel order)
        hipMemsetAsync(deg, 0, (size_t)NN * 4, stream);
        hipMemsetAsync(Sacc, 0, (size_t)NN * 64 * 4, stream);
        hipLaunchKernelGGL(k_hist, dim3((NE + 255) / 256), blk, 0, stream, ei, deg, NE);
        hipLaunchKernelGGL(k_prep, dim3(16), blk, 0, stream, W1b, b1b, W2a, Wc, bc, 0);
        hipLaunchKernelGGL(k_edge_atom, dim3((NE + 255) / 256), blk, 0, stream,
                           x, ei, ea, W1a, b1a, Sacc, NE);
        hipLaunchKernelGGL(k_node, dim3(NB), blk, 0, stream,
                           x, Sacc, deg, Wc, bc, W2a, b2a, W2b, b2b, out, NN);
    }
}